// Round 3
// baseline (2433.632 us; speedup 1.0000x reference)
//
#include <hip/hip_runtime.h>
#include <hip/hip_bf16.h>

using bf16 = __hip_bfloat16;
typedef __attribute__((ext_vector_type(8))) short short8;
typedef __attribute__((ext_vector_type(4))) float floatx4;

#define DEVFN __device__ __forceinline__

DEVFN float bf2f(bf16 v) { return __bfloat162float(v); }
DEVFN bf16 f2bf(float v) { return __float2bfloat16(v); }
DEVFN float us2f(unsigned short u) {
    union { unsigned int i; float f; } c; c.i = ((unsigned int)u) << 16; return c.f;
}
// dtype-dispatched load: isf=1 -> fp32 buffer, isf=0 -> bf16 buffer
DEVFN float loadF(const void* p, size_t i, int isf) {
    return isf ? ((const float*)p)[i] : us2f(((const unsigned short*)p)[i]);
}

// ---------------------------------------------------------------------------
// Detect input dtype: scan first 8192 half-words of x for exponent==0xFF
// patterns. fp32 N(0,1) data -> low halves are random mantissa bits -> ~16
// hits expected. Genuine bf16 N(0,1) data -> zero hits. flag=1 means fp32.
__global__ __launch_bounds__(256) void detect_kernel(const void* x, int* flag)
{
    __shared__ int any;
    if (threadIdx.x == 0) any = 0;
    __syncthreads();
    const unsigned short* p = (const unsigned short*)x;
    int hit = 0;
    for (int i = threadIdx.x; i < 8192; i += 256) {
        if ((p[i] & 0x7F80u) == 0x7F80u) hit = 1;
    }
    if (hit) any = 1;
    __syncthreads();
    if (threadIdx.x == 0) flag[0] = any;
}

// elementwise convert src (fp32 or bf16 per flag) -> bf16 dst
__global__ __launch_bounds__(256) void convert_kernel(
    const void* __restrict__ src, bf16* __restrict__ dst, const int* __restrict__ flag, int n)
{
    int isf = *flag;
    int i = blockIdx.x * 256 + threadIdx.x;
    if (i < n) dst[i] = f2bf(loadF(src, i, isf));
}

struct SegTab {
    const void* src[12];
    int off[12];
    int cnt[12];
};
// one block per small param segment -> packed bf16 params block
__global__ __launch_bounds__(256) void param_convert_kernel(
    SegTab tab, bf16* __restrict__ dst, const int* __restrict__ flag)
{
    int isf = *flag;
    int s = blockIdx.x;
    const void* src = tab.src[s];
    int off = tab.off[s], cnt = tab.cnt[s];
    for (int i = threadIdx.x; i < cnt; i += 256)
        dst[off + i] = f2bf(loadF(src, i, isf));
}

// ---------------------------------------------------------------------------
// Transpose x (B,C,N) -> t (B,N,C) fp32
__global__ __launch_bounds__(256) void transpose_in_kernel(
    const void* __restrict__ x, float* __restrict__ t, const int* __restrict__ flag,
    int C, int NN)
{
    __shared__ float tile[32][33];
    int isf = *flag;
    int b = blockIdx.z;
    int n0 = blockIdx.x * 32, c0 = blockIdx.y * 32;
    int tx = threadIdx.x, ty = threadIdx.y;
#pragma unroll
    for (int i = 0; i < 4; i++)
        tile[ty + i * 8][tx] = loadF(x, ((size_t)b * C + c0 + ty + i * 8) * NN + n0 + tx, isf);
    __syncthreads();
#pragma unroll
    for (int i = 0; i < 4; i++)
        t[((size_t)b * NN + n0 + ty + i * 8) * C + c0 + tx] = tile[tx][ty + i * 8];
}

// Transpose t (B,N,C) fp32 -> out (B,C,N) in the detected output dtype
__global__ __launch_bounds__(256) void transpose_out_kernel(
    const float* __restrict__ t, void* __restrict__ o, const int* __restrict__ flag,
    int C, int NN)
{
    __shared__ float tile[32][33];
    int isf = *flag;
    int b = blockIdx.z;
    int n0 = blockIdx.x * 32, c0 = blockIdx.y * 32;
    int tx = threadIdx.x, ty = threadIdx.y;
#pragma unroll
    for (int i = 0; i < 4; i++)
        tile[ty + i * 8][tx] = t[((size_t)b * NN + n0 + ty + i * 8) * C + c0 + tx];
    __syncthreads();
#pragma unroll
    for (int i = 0; i < 4; i++) {
        size_t oi = ((size_t)b * C + c0 + ty + i * 8) * NN + n0 + tx;
        float val = tile[tx][ty + i * 8];
        if (isf) ((float*)o)[oi] = val;
        else ((bf16*)o)[oi] = f2bf(val);
    }
}

// Transpose W (K,Nc) -> WT (Nc,K) bf16
__global__ __launch_bounds__(256) void transpose_w_kernel(
    const void* __restrict__ Wm, bf16* __restrict__ WT, const int* __restrict__ flag,
    int K, int Nc)
{
    __shared__ float tile[32][33];
    int isf = *flag;
    int n0 = blockIdx.x * 32, k0 = blockIdx.y * 32;
    int tx = threadIdx.x, ty = threadIdx.y;
#pragma unroll
    for (int i = 0; i < 4; i++)
        tile[ty + i * 8][tx] = loadF(Wm, (size_t)(k0 + ty + i * 8) * Nc + n0 + tx, isf);
    __syncthreads();
#pragma unroll
    for (int i = 0; i < 4; i++)
        WT[(size_t)(n0 + ty + i * 8) * K + k0 + tx] = f2bf(tile[tx][ty + i * 8]);
}

// ---------------------------------------------------------------------------
// LayerNorm over C=512. MODE 0: t = t + LN(t) in place (fp32).
//                       MODE 1: out = bf16(LN(t)).
template <int MODE>
__global__ __launch_bounds__(256) void ln_kernel(
    float* __restrict__ t, const bf16* __restrict__ g, const bf16* __restrict__ bta,
    bf16* __restrict__ outp, int Mrows)
{
    int w = threadIdx.x >> 6, lane = threadIdx.x & 63;
    int row = blockIdx.x * 4 + w;
    if (row >= Mrows) return;
    float* xr = t + (size_t)row * 512;
    float4 v0 = *(const float4*)(xr + lane * 8);
    float4 v1 = *(const float4*)(xr + lane * 8 + 4);
    float vals[8] = {v0.x, v0.y, v0.z, v0.w, v1.x, v1.y, v1.z, v1.w};
    float s = 0.f;
#pragma unroll
    for (int i = 0; i < 8; i++) s += vals[i];
#pragma unroll
    for (int off = 32; off; off >>= 1) s += __shfl_xor(s, off, 64);
    float mu = s * (1.f / 512.f);
    float sq = 0.f;
#pragma unroll
    for (int i = 0; i < 8; i++) { float d = vals[i] - mu; sq += d * d; }
#pragma unroll
    for (int off = 32; off; off >>= 1) sq += __shfl_xor(sq, off, 64);
    float rs = rsqrtf(sq * (1.f / 512.f) + 1e-5f);
#pragma unroll
    for (int i = 0; i < 8; i++) {
        int c = lane * 8 + i;
        float y = (vals[i] - mu) * rs * bf2f(g[c]) + bf2f(bta[c]);
        if (MODE == 0) xr[c] = vals[i] + y;
        else outp[(size_t)row * 512 + c] = f2bf(y);
    }
}

// ---------------------------------------------------------------------------
// GEMM: out(MxNc) = epilogue(A(MxK) @ WT(NcxK)^T + bias)
// MODE 0: store bf16; MODE 1: gelu(exact) then store bf16; MODE 2: += into fp32
template <int MODE>
__global__ __launch_bounds__(256) void gemm64(
    const bf16* __restrict__ A, const bf16* __restrict__ WT,
    const bf16* __restrict__ bias, void* __restrict__ outp,
    int M, int K, int Nc)
{
    __shared__ short As[64 * 32];
    __shared__ short Bs[64 * 32];
    const int tid = threadIdx.x;
    const int m0 = blockIdx.y * 64;
    const int n0 = blockIdx.x * 64;
    const int w = tid >> 6;
    const int lane = tid & 63;
    const int lm = lane & 15;
    const int lq = lane >> 4;

    floatx4 acc[4];
#pragma unroll
    for (int nb = 0; nb < 4; nb++) acc[nb] = (floatx4){0.f, 0.f, 0.f, 0.f};

    const int srow = tid >> 2;
    const int scol = (tid & 3) << 3;
    const int agrow = m0 + srow;
    const bool aok = agrow < M;
    const bf16* Aptr = A + (size_t)agrow * K + scol;
    const bf16* Bptr = WT + (size_t)(n0 + srow) * K + scol;

    for (int k0 = 0; k0 < K; k0 += 32) {
        __syncthreads();
        int4 av = make_int4(0, 0, 0, 0);
        if (aok) av = *(const int4*)(Aptr + k0);
        *(int4*)(&As[srow * 32 + scol]) = av;
        *(int4*)(&Bs[srow * 32 + scol]) = *(const int4*)(Bptr + k0);
        __syncthreads();
        short8 a = *(const short8*)(&As[(w * 16 + lm) * 32 + lq * 8]);
#pragma unroll
        for (int nb = 0; nb < 4; nb++) {
            short8 b = *(const short8*)(&Bs[(nb * 16 + lm) * 32 + lq * 8]);
            acc[nb] = __builtin_amdgcn_mfma_f32_16x16x32_bf16(a, b, acc[nb], 0, 0, 0);
        }
    }

#pragma unroll
    for (int nb = 0; nb < 4; nb++) {
        int col = n0 + nb * 16 + lm;
        float bv = bias ? bf2f(bias[col]) : 0.f;
#pragma unroll
        for (int r = 0; r < 4; r++) {
            int row = m0 + w * 16 + lq * 4 + r;
            if (row < M) {
                float v = acc[nb][r] + bv;
                if (MODE == 1) v = 0.5f * v * (1.f + erff(v * 0.70710678118654752f));
                if (MODE == 2) {
                    ((float*)outp)[(size_t)row * Nc + col] += v;
                } else {
                    ((bf16*)outp)[(size_t)row * Nc + col] = f2bf(v);
                }
            }
        }
    }
}

// ---------------------------------------------------------------------------
// Attention: o(b,n,h*64+d) = softmax(q k^T / 8) v   for one (b,h) per blockIdx.x
template <int S>
__global__ __launch_bounds__(256) void attn_kernel(
    const bf16* __restrict__ q, const bf16* __restrict__ k, const bf16* __restrict__ v,
    bf16* __restrict__ o, int N)
{
    constexpr int NJ = (S + 63) / 64;
    __shared__ unsigned short KtS[64 * S];   // [d][s]
    __shared__ unsigned short VsS[S * 64];   // [s][d]
    const int tid = threadIdx.x;
    const int b = blockIdx.x >> 3;
    const int h = blockIdx.x & 7;
    const int n0 = blockIdx.y * 64;

    for (int idx = tid * 8; idx < S * 64; idx += 2048) {
        int s = idx >> 6, dc = idx & 63;
        size_t gbase = ((size_t)(b * S + s)) * 512 + h * 64 + dc;
        short8 kv = *(const short8*)((const unsigned short*)k + gbase);
        const unsigned short* kk = (const unsigned short*)&kv;
#pragma unroll
        for (int i = 0; i < 8; i++) KtS[(dc + i) * S + s] = kk[i];
        *(short8*)(&VsS[idx]) = *(const short8*)((const unsigned short*)v + gbase);
    }
    __syncthreads();

    const int w = tid >> 6, lane = tid & 63;
    for (int iq = 0; iq < 16; iq++) {
        int n = n0 + iq * 4 + w;
        float ql = bf2f(q[((size_t)(b * N + n)) * 512 + h * 64 + lane]);
        float p[NJ];
        float mx = -1e30f;
#pragma unroll
        for (int jj = 0; jj < NJ; jj++) {
            int j = jj * 64 + lane;
            float sacc = 0.f;
#pragma unroll
            for (int d = 0; d < 64; d++) {
                float qd = __shfl(ql, d, 64);
                sacc += qd * us2f(KtS[d * S + (j < S ? j : S - 1)]);
            }
            p[jj] = (j < S) ? sacc * 0.125f : -1e30f;
            mx = fmaxf(mx, p[jj]);
        }
#pragma unroll
        for (int off = 32; off; off >>= 1) mx = fmaxf(mx, __shfl_xor(mx, off, 64));
        float sum = 0.f;
#pragma unroll
        for (int jj = 0; jj < NJ; jj++) { p[jj] = __expf(p[jj] - mx); sum += p[jj]; }
#pragma unroll
        for (int off = 32; off; off >>= 1) sum += __shfl_xor(sum, off, 64);
        float inv = 1.f / sum;
        float outv = 0.f;
#pragma unroll
        for (int jj = 0; jj < NJ; jj++) {
            float pv = p[jj];
            int jbase = jj * 64;
            int jmax = (S - jbase < 64) ? (S - jbase) : 64;
            for (int jl = 0; jl < jmax; jl++) {
                float pj = __shfl(pv, jl, 64);
                outv += pj * us2f(VsS[(jbase + jl) * 64 + lane]);
            }
        }
        o[((size_t)(b * N + n)) * 512 + h * 64 + lane] = f2bf(outv * inv);
    }
}

// ---------------------------------------------------------------------------
extern "C" void kernel_launch(void* const* d_in, const int* in_sizes, int n_in,
                              void* d_out, int out_size, void* d_ws, size_t ws_size,
                              hipStream_t stream)
{
    const void* x   = d_in[0];
    const void* ctx = d_in[1];
    const void* geo = d_in[2];
    const void* g1 = d_in[3];  const void* b1 = d_in[4];
    const void* g2 = d_in[5];  const void* b2 = d_in[6];
    const void* g3 = d_in[7];  const void* b3 = d_in[8];
    const void* g4 = d_in[9];  const void* b4 = d_in[10];
    const void* cWq = d_in[11]; const void* cWk = d_in[12];
    const void* cWv = d_in[13]; const void* cWo = d_in[14];
    const void* cbo = d_in[15];
    const void* gWq = d_in[16]; const void* gWk = d_in[17];
    const void* gWv = d_in[18]; const void* gWo = d_in[19];
    const void* gbo = d_in[20];
    const void* W1 = d_in[21];  const void* bf1 = d_in[22];
    const void* W2 = d_in[23];  const void* bf2 = d_in[24];

    const int B = 4, C = 512, NN = 4096;
    const int M = B * NN;  // 16384 token rows

    char* ws = (char*)d_ws;
    size_t off = 0;
    auto alloc = [&](size_t bytes) -> void* {
        void* p = ws + off; off += (bytes + 255) & ~(size_t)255; return p;
    };
    int*   flag = (int*)alloc(256);
    float* t  = (float*)alloc((size_t)M * C * 4);        // fp32 residual stream
    bf16* u   = (bf16*)alloc((size_t)M * C * 2);         // LN out; ob aliases u
    bf16* qb  = (bf16*)alloc((size_t)M * C * 2);         // Q; hb aliases qb
    bf16* kb  = (bf16*)alloc((size_t)B * 256 * C * 2);
    bf16* vb  = (bf16*)alloc((size_t)B * 256 * C * 2);
    bf16* ctxb = (bf16*)alloc((size_t)B * 77 * 768 * 2);
    bf16* geob = (bf16*)alloc((size_t)B * 256 * 512 * 2);
    bf16* cWqT = (bf16*)alloc((size_t)512 * 512 * 2);
    bf16* cWkT = (bf16*)alloc((size_t)512 * 768 * 2);
    bf16* cWvT = (bf16*)alloc((size_t)512 * 768 * 2);
    bf16* cWoT = (bf16*)alloc((size_t)512 * 512 * 2);
    bf16* gWqT = (bf16*)alloc((size_t)512 * 512 * 2);
    bf16* gWkT = (bf16*)alloc((size_t)512 * 512 * 2);
    bf16* gWvT = (bf16*)alloc((size_t)512 * 512 * 2);
    bf16* gWoT = (bf16*)alloc((size_t)512 * 512 * 2);
    bf16* W1T  = (bf16*)alloc((size_t)2048 * 512 * 2);
    bf16* W2T  = (bf16*)alloc((size_t)512 * 2048 * 2);
    bf16* prm  = (bf16*)alloc((size_t)7680 * 2);
    bf16* ob = u;   // attention output aliases u (u dead after Q projection)
    bf16* hb = qb;  // FFN hidden chunk aliases qb (qb dead after attention)
    (void)ws_size; (void)in_sizes; (void)n_in; (void)out_size;

    // param block layout (bf16)
    bf16 *pg1 = prm, *pb1 = prm + 512, *pg2 = prm + 1024, *pb2 = prm + 1536;
    bf16 *pg3 = prm + 2048, *pb3 = prm + 2560, *pg4 = prm + 3072, *pb4 = prm + 3584;
    bf16 *pcbo = prm + 4096, *pgbo = prm + 4608, *pbf1 = prm + 5120, *pbf2 = prm + 7168;

    dim3 tb(32, 8);

    // dtype detection + input canonicalization
    detect_kernel<<<1, 256, 0, stream>>>(x, flag);
    SegTab tab;
    const void* srcs[12] = {g1, b1, g2, b2, g3, b3, g4, b4, cbo, gbo, bf1, bf2};
    int offs[12] = {0, 512, 1024, 1536, 2048, 2560, 3072, 3584, 4096, 4608, 5120, 7168};
    int cnts[12] = {512, 512, 512, 512, 512, 512, 512, 512, 512, 512, 2048, 512};
    for (int i = 0; i < 12; i++) { tab.src[i] = srcs[i]; tab.off[i] = offs[i]; tab.cnt[i] = cnts[i]; }
    param_convert_kernel<<<12, 256, 0, stream>>>(tab, prm, flag);
    convert_kernel<<<(B * 77 * 768 + 255) / 256, 256, 0, stream>>>(ctx, ctxb, flag, B * 77 * 768);
    convert_kernel<<<(B * 256 * 512 + 255) / 256, 256, 0, stream>>>(geo, geob, flag, B * 256 * 512);

    // t = transpose(x); t = t + LN1(t)
    transpose_in_kernel<<<dim3(NN / 32, C / 32, B), tb, 0, stream>>>(x, t, flag, C, NN);
    ln_kernel<0><<<M / 4, 256, 0, stream>>>(t, pg1, pb1, nullptr, M);

    // weight transposes (W is KxN row-major -> WT NxK bf16)
    transpose_w_kernel<<<dim3(512 / 32, 512 / 32), tb, 0, stream>>>(cWq, cWqT, flag, 512, 512);
    transpose_w_kernel<<<dim3(512 / 32, 768 / 32), tb, 0, stream>>>(cWk, cWkT, flag, 768, 512);
    transpose_w_kernel<<<dim3(512 / 32, 768 / 32), tb, 0, stream>>>(cWv, cWvT, flag, 768, 512);
    transpose_w_kernel<<<dim3(512 / 32, 512 / 32), tb, 0, stream>>>(cWo, cWoT, flag, 512, 512);
    transpose_w_kernel<<<dim3(512 / 32, 512 / 32), tb, 0, stream>>>(gWq, gWqT, flag, 512, 512);
    transpose_w_kernel<<<dim3(512 / 32, 512 / 32), tb, 0, stream>>>(gWk, gWkT, flag, 512, 512);
    transpose_w_kernel<<<dim3(512 / 32, 512 / 32), tb, 0, stream>>>(gWv, gWvT, flag, 512, 512);
    transpose_w_kernel<<<dim3(512 / 32, 512 / 32), tb, 0, stream>>>(gWo, gWoT, flag, 512, 512);
    transpose_w_kernel<<<dim3(2048 / 32, 512 / 32), tb, 0, stream>>>(W1, W1T, flag, 512, 2048);
    transpose_w_kernel<<<dim3(512 / 32, 2048 / 32), tb, 0, stream>>>(W2, W2T, flag, 2048, 512);

    // ---- context cross-attention ----
    ln_kernel<1><<<M / 4, 256, 0, stream>>>(t, pg2, pb2, u, M);
    gemm64<0><<<dim3(8, M / 64), 256, 0, stream>>>(u, cWqT, nullptr, qb, M, 512, 512);
    gemm64<0><<<dim3(8, (308 + 63) / 64), 256, 0, stream>>>(ctxb, cWkT, nullptr, kb, 308, 768, 512);
    gemm64<0><<<dim3(8, (308 + 63) / 64), 256, 0, stream>>>(ctxb, cWvT, nullptr, vb, 308, 768, 512);
    attn_kernel<77><<<dim3(B * 8, NN / 64), 256, 0, stream>>>(qb, kb, vb, ob, NN);
    gemm64<2><<<dim3(8, M / 64), 256, 0, stream>>>(ob, cWoT, pcbo, t, M, 512, 512);

    // ---- geometry cross-attention ----
    ln_kernel<1><<<M / 4, 256, 0, stream>>>(t, pg3, pb3, u, M);
    gemm64<0><<<dim3(8, M / 64), 256, 0, stream>>>(u, gWqT, nullptr, qb, M, 512, 512);
    gemm64<0><<<dim3(8, 1024 / 64), 256, 0, stream>>>(geob, gWkT, nullptr, kb, 1024, 512, 512);
    gemm64<0><<<dim3(8, 1024 / 64), 256, 0, stream>>>(geob, gWvT, nullptr, vb, 1024, 512, 512);
    attn_kernel<256><<<dim3(B * 8, NN / 64), 256, 0, stream>>>(qb, kb, vb, ob, NN);
    gemm64<2><<<dim3(8, M / 64), 256, 0, stream>>>(ob, gWoT, pgbo, t, M, 512, 512);

    // ---- FFN (chunked; hidden chunk aliases qb) ----
    ln_kernel<1><<<M / 4, 256, 0, stream>>>(t, pg4, pb4, u, M);
    for (int mc = 0; mc < 4; mc++) {
        bf16* uc = u + (size_t)mc * 4096 * 512;
        float* tc = t + (size_t)mc * 4096 * 512;
        gemm64<1><<<dim3(2048 / 64, 4096 / 64), 256, 0, stream>>>(uc, W1T, pbf1, hb, 4096, 512, 2048);
        gemm64<2><<<dim3(512 / 64, 4096 / 64), 256, 0, stream>>>(hb, W2T, pbf2, tc, 4096, 2048, 512);
    }

    // out = transpose(t) in detected dtype
    transpose_out_kernel<<<dim3(NN / 32, C / 32, B), tb, 0, stream>>>(t, d_out, flag, C, NN);
}

// Round 4
// 732.520 us; speedup vs baseline: 3.3223x; 3.3223x over previous
//
#include <hip/hip_runtime.h>
#include <hip/hip_bf16.h>

using bf16 = __hip_bfloat16;
typedef __attribute__((ext_vector_type(8))) short short8;
typedef __attribute__((ext_vector_type(4))) short short4v;
typedef __attribute__((ext_vector_type(4))) float floatx4;

#define DEVFN __device__ __forceinline__

DEVFN float bf2f(bf16 v) { return __bfloat162float(v); }
DEVFN bf16 f2bf(float v) { return __float2bfloat16(v); }
DEVFN float us2f(unsigned short u) {
    union { unsigned int i; float f; } c; c.i = ((unsigned int)u) << 16; return c.f;
}
DEVFN unsigned short f2bfbits(float v) {
    union { bf16 h; unsigned short u; } c; c.h = f2bf(v); return c.u;
}
// dtype-dispatched load: isf=1 -> fp32 buffer, isf=0 -> bf16 buffer
DEVFN float loadF(const void* p, size_t i, int isf) {
    return isf ? ((const float*)p)[i] : us2f(((const unsigned short*)p)[i]);
}

// ---------------------------------------------------------------------------
// Detect input dtype: scan first 8192 half-words of x for exponent==0xFF
// patterns. fp32 N(0,1) data -> ~16 hits; bf16 data -> zero. flag=1 means fp32.
__global__ __launch_bounds__(256) void detect_kernel(const void* x, int* flag)
{
    __shared__ int any;
    if (threadIdx.x == 0) any = 0;
    __syncthreads();
    const unsigned short* p = (const unsigned short*)x;
    int hit = 0;
    for (int i = threadIdx.x; i < 8192; i += 256) {
        if ((p[i] & 0x7F80u) == 0x7F80u) hit = 1;
    }
    if (hit) any = 1;
    __syncthreads();
    if (threadIdx.x == 0) flag[0] = any;
}

// elementwise convert src (fp32 or bf16 per flag) -> bf16 dst
__global__ __launch_bounds__(256) void convert_kernel(
    const void* __restrict__ src, bf16* __restrict__ dst, const int* __restrict__ flag, int n)
{
    int isf = *flag;
    int i = blockIdx.x * 256 + threadIdx.x;
    if (i < n) dst[i] = f2bf(loadF(src, i, isf));
}

struct SegTab {
    const void* src[12];
    int off[12];
    int cnt[12];
};
__global__ __launch_bounds__(256) void param_convert_kernel(
    SegTab tab, bf16* __restrict__ dst, const int* __restrict__ flag)
{
    int isf = *flag;
    int s = blockIdx.x;
    const void* src = tab.src[s];
    int off = tab.off[s], cnt = tab.cnt[s];
    for (int i = threadIdx.x; i < cnt; i += 256)
        dst[off + i] = f2bf(loadF(src, i, isf));
}

// ---------------------------------------------------------------------------
// Transpose x (B,C,N) -> t (B,N,C) fp32
__global__ __launch_bounds__(256) void transpose_in_kernel(
    const void* __restrict__ x, float* __restrict__ t, const int* __restrict__ flag,
    int C, int NN)
{
    __shared__ float tile[32][33];
    int isf = *flag;
    int b = blockIdx.z;
    int n0 = blockIdx.x * 32, c0 = blockIdx.y * 32;
    int tx = threadIdx.x, ty = threadIdx.y;
#pragma unroll
    for (int i = 0; i < 4; i++)
        tile[ty + i * 8][tx] = loadF(x, ((size_t)b * C + c0 + ty + i * 8) * NN + n0 + tx, isf);
    __syncthreads();
#pragma unroll
    for (int i = 0; i < 4; i++)
        t[((size_t)b * NN + n0 + ty + i * 8) * C + c0 + tx] = tile[tx][ty + i * 8];
}

// Transpose t (B,N,C) fp32 -> out (B,C,N) in the detected output dtype
__global__ __launch_bounds__(256) void transpose_out_kernel(
    const float* __restrict__ t, void* __restrict__ o, const int* __restrict__ flag,
    int C, int NN)
{
    __shared__ float tile[32][33];
    int isf = *flag;
    int b = blockIdx.z;
    int n0 = blockIdx.x * 32, c0 = blockIdx.y * 32;
    int tx = threadIdx.x, ty = threadIdx.y;
#pragma unroll
    for (int i = 0; i < 4; i++)
        tile[ty + i * 8][tx] = t[((size_t)b * NN + n0 + ty + i * 8) * C + c0 + tx];
    __syncthreads();
#pragma unroll
    for (int i = 0; i < 4; i++) {
        size_t oi = ((size_t)b * C + c0 + ty + i * 8) * NN + n0 + tx;
        float val = tile[tx][ty + i * 8];
        if (isf) ((float*)o)[oi] = val;
        else ((bf16*)o)[oi] = f2bf(val);
    }
}

// Transpose W (K,Nc) -> WT (Nc,K) bf16
__global__ __launch_bounds__(256) void transpose_w_kernel(
    const void* __restrict__ Wm, bf16* __restrict__ WT, const int* __restrict__ flag,
    int K, int Nc)
{
    __shared__ float tile[32][33];
    int isf = *flag;
    int n0 = blockIdx.x * 32, k0 = blockIdx.y * 32;
    int tx = threadIdx.x, ty = threadIdx.y;
#pragma unroll
    for (int i = 0; i < 4; i++)
        tile[ty + i * 8][tx] = loadF(Wm, (size_t)(k0 + ty + i * 8) * Nc + n0 + tx, isf);
    __syncthreads();
#pragma unroll
    for (int i = 0; i < 4; i++)
        WT[(size_t)(n0 + ty + i * 8) * K + k0 + tx] = f2bf(tile[tx][ty + i * 8]);
}

// ---------------------------------------------------------------------------
// LayerNorm over C=512. MODE 0: t = t + LN(t) in place (fp32).
//                       MODE 1: out = bf16(LN(t)).
template <int MODE>
__global__ __launch_bounds__(256) void ln_kernel(
    float* __restrict__ t, const bf16* __restrict__ g, const bf16* __restrict__ bta,
    bf16* __restrict__ outp, int Mrows)
{
    int w = threadIdx.x >> 6, lane = threadIdx.x & 63;
    int row = blockIdx.x * 4 + w;
    if (row >= Mrows) return;
    float* xr = t + (size_t)row * 512;
    float4 v0 = *(const float4*)(xr + lane * 8);
    float4 v1 = *(const float4*)(xr + lane * 8 + 4);
    float vals[8] = {v0.x, v0.y, v0.z, v0.w, v1.x, v1.y, v1.z, v1.w};
    float s = 0.f;
#pragma unroll
    for (int i = 0; i < 8; i++) s += vals[i];
#pragma unroll
    for (int off = 32; off; off >>= 1) s += __shfl_xor(s, off, 64);
    float mu = s * (1.f / 512.f);
    float sq = 0.f;
#pragma unroll
    for (int i = 0; i < 8; i++) { float d = vals[i] - mu; sq += d * d; }
#pragma unroll
    for (int off = 32; off; off >>= 1) sq += __shfl_xor(sq, off, 64);
    float rs = rsqrtf(sq * (1.f / 512.f) + 1e-5f);
#pragma unroll
    for (int i = 0; i < 8; i++) {
        int c = lane * 8 + i;
        float y = (vals[i] - mu) * rs * bf2f(g[c]) + bf2f(bta[c]);
        if (MODE == 0) xr[c] = vals[i] + y;
        else outp[(size_t)row * 512 + c] = f2bf(y);
    }
}

// ---------------------------------------------------------------------------
// GEMM: out(MxNc) = epilogue(A(MxK) @ WT(NcxK)^T + bias)
// MODE 0: store bf16; MODE 1: gelu(exact) then store bf16; MODE 2: += into fp32
template <int MODE>
__global__ __launch_bounds__(256) void gemm64(
    const bf16* __restrict__ A, const bf16* __restrict__ WT,
    const bf16* __restrict__ bias, void* __restrict__ outp,
    int M, int K, int Nc)
{
    __shared__ short As[64 * 32];
    __shared__ short Bs[64 * 32];
    const int tid = threadIdx.x;
    const int m0 = blockIdx.y * 64;
    const int n0 = blockIdx.x * 64;
    const int w = tid >> 6;
    const int lane = tid & 63;
    const int lm = lane & 15;
    const int lq = lane >> 4;

    floatx4 acc[4];
#pragma unroll
    for (int nb = 0; nb < 4; nb++) acc[nb] = (floatx4){0.f, 0.f, 0.f, 0.f};

    const int srow = tid >> 2;
    const int scol = (tid & 3) << 3;
    const int agrow = m0 + srow;
    const bool aok = agrow < M;
    const bf16* Aptr = A + (size_t)agrow * K + scol;
    const bf16* Bptr = WT + (size_t)(n0 + srow) * K + scol;

    for (int k0 = 0; k0 < K; k0 += 32) {
        __syncthreads();
        int4 av = make_int4(0, 0, 0, 0);
        if (aok) av = *(const int4*)(Aptr + k0);
        *(int4*)(&As[srow * 32 + scol]) = av;
        *(int4*)(&Bs[srow * 32 + scol]) = *(const int4*)(Bptr + k0);
        __syncthreads();
        short8 a = *(const short8*)(&As[(w * 16 + lm) * 32 + lq * 8]);
#pragma unroll
        for (int nb = 0; nb < 4; nb++) {
            short8 b = *(const short8*)(&Bs[(nb * 16 + lm) * 32 + lq * 8]);
            acc[nb] = __builtin_amdgcn_mfma_f32_16x16x32_bf16(a, b, acc[nb], 0, 0, 0);
        }
    }

#pragma unroll
    for (int nb = 0; nb < 4; nb++) {
        int col = n0 + nb * 16 + lm;
        float bv = bias ? bf2f(bias[col]) : 0.f;
#pragma unroll
        for (int r = 0; r < 4; r++) {
            int row = m0 + w * 16 + lq * 4 + r;
            if (row < M) {
                float v = acc[nb][r] + bv;
                if (MODE == 1) v = 0.5f * v * (1.f + erff(v * 0.70710678118654752f));
                if (MODE == 2) {
                    ((float*)outp)[(size_t)row * Nc + col] += v;
                } else {
                    ((bf16*)outp)[(size_t)row * Nc + col] = f2bf(v);
                }
            }
        }
    }
}

// ---------------------------------------------------------------------------
// MFMA attention. Block = one (b,h) x 64-query tile; 4 waves, 16 q each.
// Computes S^T = K·Q^T (MFMA), softmax over s (per-lane + 2 shuffles),
// P via LDS round-trip (B-fragment layout), O^T = V^T·P^T (MFMA),
// O transposed through LDS for coalesced stores.
// LDS: Ks[s][64] swizzled + Vt[d][SPAD] swizzled; P aliases Ks after barrier.
template <int SPAD, int SVALID>
__global__ __launch_bounds__(256) void attn_mfma_kernel(
    const bf16* __restrict__ q, const bf16* __restrict__ k, const bf16* __restrict__ v,
    bf16* __restrict__ o, int N)
{
    constexpr int MB = SPAD / 16;   // score m-blocks over s
    constexpr int KS = SPAD / 32;   // PV k-steps over s
    __shared__ unsigned short lds[SPAD * 64 + 64 * SPAD];
    unsigned short* Ks = lds;                 // [s][64], chunk-swizzled by s&7
    unsigned short* Vt = lds + SPAD * 64;     // [d][SPAD], chunk-swizzled by d&7
    unsigned short* Pw = lds;                 // alias (after barrier): per-wave [16][SPAD]

    const int tid = threadIdx.x;
    const int b = blockIdx.x >> 3;
    const int h = blockIdx.x & 7;
    const int n0 = blockIdx.y * 64;
    const int w = tid >> 6, lane = tid & 63;
    const int lm = lane & 15, lq = lane >> 4;

    // ---- stage K[s][d] and V^T[d][s] (zero-padded past SVALID) ----
    const unsigned short* kp = (const unsigned short*)k;
    const unsigned short* vp = (const unsigned short*)v;
    for (int idx = tid * 8; idx < SPAD * 64; idx += 2048) {
        int s = idx >> 6, d0 = idx & 63;
        short8 kv = {0, 0, 0, 0, 0, 0, 0, 0};
        short8 vv = {0, 0, 0, 0, 0, 0, 0, 0};
        if (s < SVALID) {
            size_t gb = ((size_t)(b * SVALID + s)) * 512 + h * 64 + d0;
            kv = *(const short8*)(kp + gb);
            vv = *(const short8*)(vp + gb);
        }
        int kc = (d0 >> 3) ^ (s & 7);
        *(short8*)(&Ks[s * 64 + kc * 8]) = kv;
        const unsigned short* vvp = (const unsigned short*)&vv;
#pragma unroll
        for (int i = 0; i < 8; i++) {
            int d = d0 + i;
            int sc = (s >> 3) ^ (d & 7);
            Vt[d * SPAD + sc * 8 + (s & 7)] = vvp[i];
        }
    }

    // ---- Q B-fragments straight from global: B[k=d][n=q] = Q[q0+lm][d] ----
    const int q0 = n0 + w * 16;
    const unsigned short* qp = (const unsigned short*)q;
    size_t qbase = ((size_t)(b * N + q0 + lm)) * 512 + h * 64 + lq * 8;
    short8 qf0 = *(const short8*)(qp + qbase);
    short8 qf1 = *(const short8*)(qp + qbase + 32);
    __syncthreads();

    // ---- scores S^T = K Q^T : m=s (MB blocks), n=this wave's 16 q, k=d ----
    floatx4 sacc[MB];
#pragma unroll
    for (int mb = 0; mb < MB; mb++) sacc[mb] = (floatx4){0.f, 0.f, 0.f, 0.f};
#pragma unroll
    for (int mb = 0; mb < MB; mb++) {
        int srow = mb * 16 + lm;
        short8 a0 = *(const short8*)(&Ks[srow * 64 + ((lq ^ (lm & 7)) * 8)]);
        short8 a1 = *(const short8*)(&Ks[srow * 64 + (((4 + lq) ^ (lm & 7)) * 8)]);
        sacc[mb] = __builtin_amdgcn_mfma_f32_16x16x32_bf16(a0, qf0, sacc[mb], 0, 0, 0);
        sacc[mb] = __builtin_amdgcn_mfma_f32_16x16x32_bf16(a1, qf1, sacc[mb], 0, 0, 0);
    }

    // ---- softmax over s (lane holds s = mb*16 + lq*4 + r for q = q0+lm) ----
    float mx = -1e30f;
#pragma unroll
    for (int mb = 0; mb < MB; mb++)
#pragma unroll
        for (int r = 0; r < 4; r++) {
            int s = mb * 16 + lq * 4 + r;
            if (s < SVALID) mx = fmaxf(mx, sacc[mb][r]);
        }
    mx = fmaxf(mx, __shfl_xor(mx, 16, 64));
    mx = fmaxf(mx, __shfl_xor(mx, 32, 64));
    mx *= 0.125f;
    float sum = 0.f;
#pragma unroll
    for (int mb = 0; mb < MB; mb++)
#pragma unroll
        for (int r = 0; r < 4; r++) {
            int s = mb * 16 + lq * 4 + r;
            float e = (s < SVALID) ? __expf(sacc[mb][r] * 0.125f - mx) : 0.f;
            sacc[mb][r] = e;
            sum += e;
        }
    sum += __shfl_xor(sum, 16, 64);
    sum += __shfl_xor(sum, 32, 64);
    float inv = 1.f / sum;

    __syncthreads();  // everyone done reading Ks before P overwrites it

    // ---- write P (normalized bf16) into per-wave region, layout [q][s] ----
    unsigned short* Pme = Pw + w * 16 * SPAD;
#pragma unroll
    for (int mb = 0; mb < MB; mb++) {
        short4v pk;
        pk[0] = (short)f2bfbits(sacc[mb][0] * inv);
        pk[1] = (short)f2bfbits(sacc[mb][1] * inv);
        pk[2] = (short)f2bfbits(sacc[mb][2] * inv);
        pk[3] = (short)f2bfbits(sacc[mb][3] * inv);
        int chunk = (mb * 2 + (lq >> 1)) ^ (lm & 7);
        *(short4v*)(&Pme[lm * SPAD + chunk * 8 + (lq & 1) * 4]) = pk;
    }

    // ---- O^T = V^T P^T : m=d (4 blocks), n=16 q, k=s (KS steps) ----
    floatx4 oacc[4];
#pragma unroll
    for (int mb2 = 0; mb2 < 4; mb2++) oacc[mb2] = (floatx4){0.f, 0.f, 0.f, 0.f};
    for (int ks = 0; ks < KS; ks++) {
        int sch = ((ks * 4 + lq) ^ (lm & 7)) * 8;
        short8 bfrag = *(const short8*)(&Pme[lm * SPAD + sch]);
#pragma unroll
        for (int mb2 = 0; mb2 < 4; mb2++) {
            int d = mb2 * 16 + lm;
            short8 afrag = *(const short8*)(&Vt[d * SPAD + sch]);
            oacc[mb2] = __builtin_amdgcn_mfma_f32_16x16x32_bf16(afrag, bfrag, oacc[mb2], 0, 0, 0);
        }
    }

    // ---- O^T -> per-wave LDS [q][64] (stride 64, swizzled) -> coalesced store
#pragma unroll
    for (int mb2 = 0; mb2 < 4; mb2++) {
        short4v ok;
        ok[0] = (short)f2bfbits(oacc[mb2][0]);
        ok[1] = (short)f2bfbits(oacc[mb2][1]);
        ok[2] = (short)f2bfbits(oacc[mb2][2]);
        ok[3] = (short)f2bfbits(oacc[mb2][3]);
        int chunk = (mb2 * 2 + (lq >> 1)) ^ (lm & 7);
        *(short4v*)(&Pme[lm * 64 + chunk * 8 + (lq & 1) * 4]) = ok;
    }
    unsigned short* op = (unsigned short*)o;
#pragma unroll
    for (int p = 0; p < 2; p++) {
        int row = p * 8 + (lane >> 3);
        int chunk = lane & 7;
        short8 ov = *(const short8*)(&Pme[row * 64 + ((chunk ^ (row & 7)) * 8)]);
        *(short8*)(op + ((size_t)(b * N + n0 + w * 16 + row)) * 512 + h * 64 + chunk * 8) = ov;
    }
}

// ---------------------------------------------------------------------------
extern "C" void kernel_launch(void* const* d_in, const int* in_sizes, int n_in,
                              void* d_out, int out_size, void* d_ws, size_t ws_size,
                              hipStream_t stream)
{
    const void* x   = d_in[0];
    const void* ctx = d_in[1];
    const void* geo = d_in[2];
    const void* g1 = d_in[3];  const void* b1 = d_in[4];
    const void* g2 = d_in[5];  const void* b2 = d_in[6];
    const void* g3 = d_in[7];  const void* b3 = d_in[8];
    const void* g4 = d_in[9];  const void* b4 = d_in[10];
    const void* cWq = d_in[11]; const void* cWk = d_in[12];
    const void* cWv = d_in[13]; const void* cWo = d_in[14];
    const void* cbo = d_in[15];
    const void* gWq = d_in[16]; const void* gWk = d_in[17];
    const void* gWv = d_in[18]; const void* gWo = d_in[19];
    const void* gbo = d_in[20];
    const void* W1 = d_in[21];  const void* bf1 = d_in[22];
    const void* W2 = d_in[23];  const void* bf2 = d_in[24];

    const int B = 4, C = 512, NN = 4096;
    const int M = B * NN;  // 16384 token rows

    char* ws = (char*)d_ws;
    size_t off = 0;
    auto alloc = [&](size_t bytes) -> void* {
        void* p = ws + off; off += (bytes + 255) & ~(size_t)255; return p;
    };
    int*   flag = (int*)alloc(256);
    float* t  = (float*)alloc((size_t)M * C * 4);        // fp32 residual stream
    bf16* u   = (bf16*)alloc((size_t)M * C * 2);         // LN out; ob aliases u
    bf16* qb  = (bf16*)alloc((size_t)M * C * 2);         // Q; hb aliases qb
    bf16* kb  = (bf16*)alloc((size_t)B * 256 * C * 2);
    bf16* vb  = (bf16*)alloc((size_t)B * 256 * C * 2);
    bf16* ctxb = (bf16*)alloc((size_t)B * 77 * 768 * 2);
    bf16* geob = (bf16*)alloc((size_t)B * 256 * 512 * 2);
    bf16* cWqT = (bf16*)alloc((size_t)512 * 512 * 2);
    bf16* cWkT = (bf16*)alloc((size_t)512 * 768 * 2);
    bf16* cWvT = (bf16*)alloc((size_t)512 * 768 * 2);
    bf16* cWoT = (bf16*)alloc((size_t)512 * 512 * 2);
    bf16* gWqT = (bf16*)alloc((size_t)512 * 512 * 2);
    bf16* gWkT = (bf16*)alloc((size_t)512 * 512 * 2);
    bf16* gWvT = (bf16*)alloc((size_t)512 * 512 * 2);
    bf16* gWoT = (bf16*)alloc((size_t)512 * 512 * 2);
    bf16* W1T  = (bf16*)alloc((size_t)2048 * 512 * 2);
    bf16* W2T  = (bf16*)alloc((size_t)512 * 2048 * 2);
    bf16* prm  = (bf16*)alloc((size_t)7680 * 2);
    bf16* ob = u;   // attention output aliases u (u dead after Q projection)
    bf16* hb = qb;  // FFN hidden chunk aliases qb (qb dead after attention)
    (void)ws_size; (void)in_sizes; (void)n_in; (void)out_size;

    // param block layout (bf16)
    bf16 *pg1 = prm, *pb1 = prm + 512, *pg2 = prm + 1024, *pb2 = prm + 1536;
    bf16 *pg3 = prm + 2048, *pb3 = prm + 2560, *pg4 = prm + 3072, *pb4 = prm + 3584;
    bf16 *pcbo = prm + 4096, *pgbo = prm + 4608, *pbf1 = prm + 5120, *pbf2 = prm + 7168;

    dim3 tb(32, 8);

    // dtype detection + input canonicalization
    detect_kernel<<<1, 256, 0, stream>>>(x, flag);
    SegTab tab;
    const void* srcs[12] = {g1, b1, g2, b2, g3, b3, g4, b4, cbo, gbo, bf1, bf2};
    int offs[12] = {0, 512, 1024, 1536, 2048, 2560, 3072, 3584, 4096, 4608, 5120, 7168};
    int cnts[12] = {512, 512, 512, 512, 512, 512, 512, 512, 512, 512, 2048, 512};
    for (int i = 0; i < 12; i++) { tab.src[i] = srcs[i]; tab.off[i] = offs[i]; tab.cnt[i] = cnts[i]; }
    param_convert_kernel<<<12, 256, 0, stream>>>(tab, prm, flag);
    convert_kernel<<<(B * 77 * 768 + 255) / 256, 256, 0, stream>>>(ctx, ctxb, flag, B * 77 * 768);
    convert_kernel<<<(B * 256 * 512 + 255) / 256, 256, 0, stream>>>(geo, geob, flag, B * 256 * 512);

    // t = transpose(x); t = t + LN1(t)
    transpose_in_kernel<<<dim3(NN / 32, C / 32, B), tb, 0, stream>>>(x, t, flag, C, NN);
    ln_kernel<0><<<M / 4, 256, 0, stream>>>(t, pg1, pb1, nullptr, M);

    // weight transposes (W is KxN row-major -> WT NxK bf16)
    transpose_w_kernel<<<dim3(512 / 32, 512 / 32), tb, 0, stream>>>(cWq, cWqT, flag, 512, 512);
    transpose_w_kernel<<<dim3(512 / 32, 768 / 32), tb, 0, stream>>>(cWk, cWkT, flag, 768, 512);
    transpose_w_kernel<<<dim3(512 / 32, 768 / 32), tb, 0, stream>>>(cWv, cWvT, flag, 768, 512);
    transpose_w_kernel<<<dim3(512 / 32, 512 / 32), tb, 0, stream>>>(cWo, cWoT, flag, 512, 512);
    transpose_w_kernel<<<dim3(512 / 32, 512 / 32), tb, 0, stream>>>(gWq, gWqT, flag, 512, 512);
    transpose_w_kernel<<<dim3(512 / 32, 512 / 32), tb, 0, stream>>>(gWk, gWkT, flag, 512, 512);
    transpose_w_kernel<<<dim3(512 / 32, 512 / 32), tb, 0, stream>>>(gWv, gWvT, flag, 512, 512);
    transpose_w_kernel<<<dim3(512 / 32, 512 / 32), tb, 0, stream>>>(gWo, gWoT, flag, 512, 512);
    transpose_w_kernel<<<dim3(2048 / 32, 512 / 32), tb, 0, stream>>>(W1, W1T, flag, 512, 2048);
    transpose_w_kernel<<<dim3(512 / 32, 2048 / 32), tb, 0, stream>>>(W2, W2T, flag, 2048, 512);

    // ---- context cross-attention ----
    ln_kernel<1><<<M / 4, 256, 0, stream>>>(t, pg2, pb2, u, M);
    gemm64<0><<<dim3(8, M / 64), 256, 0, stream>>>(u, cWqT, nullptr, qb, M, 512, 512);
    gemm64<0><<<dim3(8, (308 + 63) / 64), 256, 0, stream>>>(ctxb, cWkT, nullptr, kb, 308, 768, 512);
    gemm64<0><<<dim3(8, (308 + 63) / 64), 256, 0, stream>>>(ctxb, cWvT, nullptr, vb, 308, 768, 512);
    attn_mfma_kernel<128, 77><<<dim3(B * 8, NN / 64), 256, 0, stream>>>(qb, kb, vb, ob, NN);
    gemm64<2><<<dim3(8, M / 64), 256, 0, stream>>>(ob, cWoT, pcbo, t, M, 512, 512);

    // ---- geometry cross-attention ----
    ln_kernel<1><<<M / 4, 256, 0, stream>>>(t, pg3, pb3, u, M);
    gemm64<0><<<dim3(8, M / 64), 256, 0, stream>>>(u, gWqT, nullptr, qb, M, 512, 512);
    gemm64<0><<<dim3(8, 1024 / 64), 256, 0, stream>>>(geob, gWkT, nullptr, kb, 1024, 512, 512);
    gemm64<0><<<dim3(8, 1024 / 64), 256, 0, stream>>>(geob, gWvT, nullptr, vb, 1024, 512, 512);
    attn_mfma_kernel<256, 256><<<dim3(B * 8, NN / 64), 256, 0, stream>>>(qb, kb, vb, ob, NN);
    gemm64<2><<<dim3(8, M / 64), 256, 0, stream>>>(ob, gWoT, pgbo, t, M, 512, 512);

    // ---- FFN (chunked; hidden chunk aliases qb) ----
    ln_kernel<1><<<M / 4, 256, 0, stream>>>(t, pg4, pb4, u, M);
    for (int mc = 0; mc < 4; mc++) {
        bf16* uc = u + (size_t)mc * 4096 * 512;
        float* tc = t + (size_t)mc * 4096 * 512;
        gemm64<1><<<dim3(2048 / 64, 4096 / 64), 256, 0, stream>>>(uc, W1T, pbf1, hb, 4096, 512, 2048);
        gemm64<2><<<dim3(512 / 64, 4096 / 64), 256, 0, stream>>>(hb, W2T, pbf2, tc, 4096, 2048, 512);
    }

    // out = transpose(t) in detected dtype
    transpose_out_kernel<<<dim3(NN / 32, C / 32, B), tb, 0, stream>>>(t, d_out, flag, C, NN);
}

// Round 5
// 595.015 us; speedup vs baseline: 4.0900x; 1.2311x over previous
//
#include <hip/hip_runtime.h>
#include <hip/hip_bf16.h>

using bf16 = __hip_bfloat16;
typedef __attribute__((ext_vector_type(8))) short short8;
typedef __attribute__((ext_vector_type(4))) short short4v;
typedef __attribute__((ext_vector_type(4))) float floatx4;

#define DEVFN __device__ __forceinline__

DEVFN float bf2f(bf16 v) { return __bfloat162float(v); }
DEVFN bf16 f2bf(float v) { return __float2bfloat16(v); }
DEVFN float us2f(unsigned short u) {
    union { unsigned int i; float f; } c; c.i = ((unsigned int)u) << 16; return c.f;
}
DEVFN unsigned short f2bfbits(float v) {
    union { bf16 h; unsigned short u; } c; c.h = f2bf(v); return c.u;
}
// dtype-dispatched load: isf=1 -> fp32 buffer, isf=0 -> bf16 buffer
DEVFN float loadF(const void* p, size_t i, int isf) {
    return isf ? ((const float*)p)[i] : us2f(((const unsigned short*)p)[i]);
}
// async global->LDS, 16B per lane; lds dest = wave-uniform base + lane*16
DEVFN void gl_lds16(const bf16* g, short* l) {
    __builtin_amdgcn_global_load_lds(
        (const __attribute__((address_space(1))) unsigned int*)g,
        (__attribute__((address_space(3))) unsigned int*)l, 16, 0, 0);
}

// ---------------------------------------------------------------------------
// Detect input dtype: fp32 N(0,1) -> low halves random -> exp==0xFF hits.
__global__ __launch_bounds__(256) void detect_kernel(const void* x, int* flag)
{
    __shared__ int any;
    if (threadIdx.x == 0) any = 0;
    __syncthreads();
    const unsigned short* p = (const unsigned short*)x;
    int hit = 0;
    for (int i = threadIdx.x; i < 8192; i += 256) {
        if ((p[i] & 0x7F80u) == 0x7F80u) hit = 1;
    }
    if (hit) any = 1;
    __syncthreads();
    if (threadIdx.x == 0) flag[0] = any;
}

__global__ __launch_bounds__(256) void convert_kernel(
    const void* __restrict__ src, bf16* __restrict__ dst, const int* __restrict__ flag, int n)
{
    int isf = *flag;
    int i = blockIdx.x * 256 + threadIdx.x;
    if (i < n) dst[i] = f2bf(loadF(src, i, isf));
}

struct SegTab {
    const void* src[12];
    int off[12];
    int cnt[12];
};
__global__ __launch_bounds__(256) void param_convert_kernel(
    SegTab tab, bf16* __restrict__ dst, const int* __restrict__ flag)
{
    int isf = *flag;
    int s = blockIdx.x;
    const void* src = tab.src[s];
    int off = tab.off[s], cnt = tab.cnt[s];
    for (int i = threadIdx.x; i < cnt; i += 256)
        dst[off + i] = f2bf(loadF(src, i, isf));
}

// ---------------------------------------------------------------------------
// Transpose x (B,C,N) -> t (B,N,C) fp32
__global__ __launch_bounds__(256) void transpose_in_kernel(
    const void* __restrict__ x, float* __restrict__ t, const int* __restrict__ flag,
    int C, int NN)
{
    __shared__ float tile[32][33];
    int isf = *flag;
    int b = blockIdx.z;
    int n0 = blockIdx.x * 32, c0 = blockIdx.y * 32;
    int tx = threadIdx.x, ty = threadIdx.y;
#pragma unroll
    for (int i = 0; i < 4; i++)
        tile[ty + i * 8][tx] = loadF(x, ((size_t)b * C + c0 + ty + i * 8) * NN + n0 + tx, isf);
    __syncthreads();
#pragma unroll
    for (int i = 0; i < 4; i++)
        t[((size_t)b * NN + n0 + ty + i * 8) * C + c0 + tx] = tile[tx][ty + i * 8];
}

// Transpose t (B,N,C) fp32 -> out (B,C,N) in the detected output dtype
__global__ __launch_bounds__(256) void transpose_out_kernel(
    const float* __restrict__ t, void* __restrict__ o, const int* __restrict__ flag,
    int C, int NN)
{
    __shared__ float tile[32][33];
    int isf = *flag;
    int b = blockIdx.z;
    int n0 = blockIdx.x * 32, c0 = blockIdx.y * 32;
    int tx = threadIdx.x, ty = threadIdx.y;
#pragma unroll
    for (int i = 0; i < 4; i++)
        tile[ty + i * 8][tx] = t[((size_t)b * NN + n0 + ty + i * 8) * C + c0 + tx];
    __syncthreads();
#pragma unroll
    for (int i = 0; i < 4; i++) {
        size_t oi = ((size_t)b * C + c0 + ty + i * 8) * NN + n0 + tx;
        float val = tile[tx][ty + i * 8];
        if (isf) ((float*)o)[oi] = val;
        else ((bf16*)o)[oi] = f2bf(val);
    }
}

// Transpose W (K,Nc) -> WT (Nc,K) bf16
__global__ __launch_bounds__(256) void transpose_w_kernel(
    const void* __restrict__ Wm, bf16* __restrict__ WT, const int* __restrict__ flag,
    int K, int Nc)
{
    __shared__ float tile[32][33];
    int isf = *flag;
    int n0 = blockIdx.x * 32, k0 = blockIdx.y * 32;
    int tx = threadIdx.x, ty = threadIdx.y;
#pragma unroll
    for (int i = 0; i < 4; i++)
        tile[ty + i * 8][tx] = loadF(Wm, (size_t)(k0 + ty + i * 8) * Nc + n0 + tx, isf);
    __syncthreads();
#pragma unroll
    for (int i = 0; i < 4; i++)
        WT[(size_t)(n0 + ty + i * 8) * K + k0 + tx] = f2bf(tile[tx][ty + i * 8]);
}

// ---------------------------------------------------------------------------
// LayerNorm over C=512. MODE 0: t = t + LN(t) in place (fp32).
//                       MODE 1: out = bf16(LN(t)).
template <int MODE>
__global__ __launch_bounds__(256) void ln_kernel(
    float* __restrict__ t, const bf16* __restrict__ g, const bf16* __restrict__ bta,
    bf16* __restrict__ outp, int Mrows)
{
    int w = threadIdx.x >> 6, lane = threadIdx.x & 63;
    int row = blockIdx.x * 4 + w;
    if (row >= Mrows) return;
    float* xr = t + (size_t)row * 512;
    float4 v0 = *(const float4*)(xr + lane * 8);
    float4 v1 = *(const float4*)(xr + lane * 8 + 4);
    float vals[8] = {v0.x, v0.y, v0.z, v0.w, v1.x, v1.y, v1.z, v1.w};
    float s = 0.f;
#pragma unroll
    for (int i = 0; i < 8; i++) s += vals[i];
#pragma unroll
    for (int off = 32; off; off >>= 1) s += __shfl_xor(s, off, 64);
    float mu = s * (1.f / 512.f);
    float sq = 0.f;
#pragma unroll
    for (int i = 0; i < 8; i++) { float d = vals[i] - mu; sq += d * d; }
#pragma unroll
    for (int off = 32; off; off >>= 1) sq += __shfl_xor(sq, off, 64);
    float rs = rsqrtf(sq * (1.f / 512.f) + 1e-5f);
#pragma unroll
    for (int i = 0; i < 8; i++) {
        int c = lane * 8 + i;
        float y = (vals[i] - mu) * rs * bf2f(g[c]) + bf2f(bta[c]);
        if (MODE == 0) xr[c] = vals[i] + y;
        else outp[(size_t)row * 512 + c] = f2bf(y);
    }
}

// ---------------------------------------------------------------------------
// 64-tile GEMM (kept for small/ragged M): out = epi(A @ WT^T + bias)
template <int MODE>
__global__ __launch_bounds__(256) void gemm64(
    const bf16* __restrict__ A, const bf16* __restrict__ WT,
    const bf16* __restrict__ bias, void* __restrict__ outp,
    int M, int K, int Nc)
{
    __shared__ short As[64 * 32];
    __shared__ short Bs[64 * 32];
    const int tid = threadIdx.x;
    const int m0 = blockIdx.y * 64;
    const int n0 = blockIdx.x * 64;
    const int w = tid >> 6;
    const int lane = tid & 63;
    const int lm = lane & 15;
    const int lq = lane >> 4;

    floatx4 acc[4];
#pragma unroll
    for (int nb = 0; nb < 4; nb++) acc[nb] = (floatx4){0.f, 0.f, 0.f, 0.f};

    const int srow = tid >> 2;
    const int scol = (tid & 3) << 3;
    const int agrow = m0 + srow;
    const bool aok = agrow < M;
    const bf16* Aptr = A + (size_t)agrow * K + scol;
    const bf16* Bptr = WT + (size_t)(n0 + srow) * K + scol;

    for (int k0 = 0; k0 < K; k0 += 32) {
        __syncthreads();
        int4 av = make_int4(0, 0, 0, 0);
        if (aok) av = *(const int4*)(Aptr + k0);
        *(int4*)(&As[srow * 32 + scol]) = av;
        *(int4*)(&Bs[srow * 32 + scol]) = *(const int4*)(Bptr + k0);
        __syncthreads();
        short8 a = *(const short8*)(&As[(w * 16 + lm) * 32 + lq * 8]);
#pragma unroll
        for (int nb = 0; nb < 4; nb++) {
            short8 b = *(const short8*)(&Bs[(nb * 16 + lm) * 32 + lq * 8]);
            acc[nb] = __builtin_amdgcn_mfma_f32_16x16x32_bf16(a, b, acc[nb], 0, 0, 0);
        }
    }

#pragma unroll
    for (int nb = 0; nb < 4; nb++) {
        int col = n0 + nb * 16 + lm;
        float bv = bias ? bf2f(bias[col]) : 0.f;
#pragma unroll
        for (int r = 0; r < 4; r++) {
            int row = m0 + w * 16 + lq * 4 + r;
            if (row < M) {
                float v = acc[nb][r] + bv;
                if (MODE == 1) v = 0.5f * v * (1.f + erff(v * 0.70710678118654752f));
                if (MODE == 2) {
                    ((float*)outp)[(size_t)row * Nc + col] += v;
                } else {
                    ((bf16*)outp)[(size_t)row * Nc + col] = f2bf(v);
                }
            }
        }
    }
}

// ---------------------------------------------------------------------------
// 128-tile GEMM, m97 structure: BK=32, global_load_lds width=16 staging,
// 4 waves in 2x2 quadrants, 16 MFMA/iter. REQUIRES M%128==0, N%128==0, K%32==0.
// MODE 0: store bf16; MODE 1: gelu then bf16; MODE 2: += into fp32
template <int MODE>
__global__ __launch_bounds__(256) void gemm128(
    const bf16* __restrict__ A, const bf16* __restrict__ WT,
    const bf16* __restrict__ bias, void* __restrict__ outp,
    int K, int Nc)
{
    __shared__ short As[128 * 32];
    __shared__ short Bs[128 * 32];
    const int tid = threadIdx.x;
    const int m0 = blockIdx.y * 128;
    const int n0 = blockIdx.x * 128;
    const int w = tid >> 6, lane = tid & 63;
    const int lm = lane & 15, lq = lane >> 4;
    const int wm = w >> 1, wn = w & 1;

    floatx4 acc[4][4];
#pragma unroll
    for (int mb = 0; mb < 4; mb++)
#pragma unroll
        for (int nb = 0; nb < 4; nb++) acc[mb][nb] = (floatx4){0.f, 0.f, 0.f, 0.f};

    // staging: 8 chunks of 1KB each for A and B; wave w handles chunks w*2, w*2+1.
    // chunk ci covers rows ci*16..+15, LDS [row][32] row-major; lane i -> 16B at
    // base + i*16 == row (ci*16 + i/4), k-chunk (i%4)*8 — matches global addr.
    const int c0 = w * 2, c1 = w * 2 + 1;
    const int lr = lane >> 2;
    const int lk = (lane & 3) << 3;
    const bf16* gA0 = A + (size_t)(m0 + c0 * 16 + lr) * K + lk;
    const bf16* gA1 = A + (size_t)(m0 + c1 * 16 + lr) * K + lk;
    const bf16* gB0 = WT + (size_t)(n0 + c0 * 16 + lr) * K + lk;
    const bf16* gB1 = WT + (size_t)(n0 + c1 * 16 + lr) * K + lk;
    short* lA0 = &As[c0 * 512];
    short* lA1 = &As[c1 * 512];
    short* lB0 = &Bs[c0 * 512];
    short* lB1 = &Bs[c1 * 512];

    for (int k0 = 0; k0 < K; k0 += 32) {
        gl_lds16(gA0 + k0, lA0);
        gl_lds16(gA1 + k0, lA1);
        gl_lds16(gB0 + k0, lB0);
        gl_lds16(gB1 + k0, lB1);
        __syncthreads();
        short8 af[4], bfr[4];
#pragma unroll
        for (int mb = 0; mb < 4; mb++)
            af[mb] = *(const short8*)(&As[(wm * 64 + mb * 16 + lm) * 32 + lq * 8]);
#pragma unroll
        for (int nb = 0; nb < 4; nb++)
            bfr[nb] = *(const short8*)(&Bs[(wn * 64 + nb * 16 + lm) * 32 + lq * 8]);
#pragma unroll
        for (int mb = 0; mb < 4; mb++)
#pragma unroll
            for (int nb = 0; nb < 4; nb++)
                acc[mb][nb] = __builtin_amdgcn_mfma_f32_16x16x32_bf16(af[mb], bfr[nb], acc[mb][nb], 0, 0, 0);
        __syncthreads();
    }

#pragma unroll
    for (int nb = 0; nb < 4; nb++) {
        int col = n0 + wn * 64 + nb * 16 + lm;
        float bv = bias ? bf2f(bias[col]) : 0.f;
#pragma unroll
        for (int mb = 0; mb < 4; mb++) {
#pragma unroll
            for (int r = 0; r < 4; r++) {
                size_t row = m0 + wm * 64 + mb * 16 + lq * 4 + r;
                float v = acc[mb][nb][r] + bv;
                if (MODE == 1) v = 0.5f * v * (1.f + erff(v * 0.70710678118654752f));
                if (MODE == 2) {
                    ((float*)outp)[row * Nc + col] += v;
                } else {
                    ((bf16*)outp)[row * Nc + col] = f2bf(v);
                }
            }
        }
    }
}

// ---------------------------------------------------------------------------
// MFMA attention. Block = one (b,h) x 64-query tile; 4 waves, 16 q each.
template <int SPAD, int SVALID>
__global__ __launch_bounds__(256) void attn_mfma_kernel(
    const bf16* __restrict__ q, const bf16* __restrict__ k, const bf16* __restrict__ v,
    bf16* __restrict__ o, int N)
{
    constexpr int MB = SPAD / 16;   // score m-blocks over s
    constexpr int KS = SPAD / 32;   // PV k-steps over s
    __shared__ unsigned short lds[SPAD * 64 + 64 * SPAD];
    unsigned short* Ks = lds;                 // [s][64], chunk-swizzled by s&7
    unsigned short* Vt = lds + SPAD * 64;     // [d][SPAD], chunk-swizzled by d&7
    unsigned short* Pw = lds;                 // alias (after barrier): per-wave [16][SPAD]

    const int tid = threadIdx.x;
    const int b = blockIdx.x >> 3;
    const int h = blockIdx.x & 7;
    const int n0 = blockIdx.y * 64;
    const int w = tid >> 6, lane = tid & 63;
    const int lm = lane & 15, lq = lane >> 4;

    const unsigned short* kp = (const unsigned short*)k;
    const unsigned short* vp = (const unsigned short*)v;
    for (int idx = tid * 8; idx < SPAD * 64; idx += 2048) {
        int s = idx >> 6, d0 = idx & 63;
        short8 kv = {0, 0, 0, 0, 0, 0, 0, 0};
        short8 vv = {0, 0, 0, 0, 0, 0, 0, 0};
        if (s < SVALID) {
            size_t gb = ((size_t)(b * SVALID + s)) * 512 + h * 64 + d0;
            kv = *(const short8*)(kp + gb);
            vv = *(const short8*)(vp + gb);
        }
        int kc = (d0 >> 3) ^ (s & 7);
        *(short8*)(&Ks[s * 64 + kc * 8]) = kv;
        const unsigned short* vvp = (const unsigned short*)&vv;
#pragma unroll
        for (int i = 0; i < 8; i++) {
            int d = d0 + i;
            int sc = (s >> 3) ^ (d & 7);
            Vt[d * SPAD + sc * 8 + (s & 7)] = vvp[i];
        }
    }

    const int q0 = n0 + w * 16;
    const unsigned short* qp = (const unsigned short*)q;
    size_t qbase = ((size_t)(b * N + q0 + lm)) * 512 + h * 64 + lq * 8;
    short8 qf0 = *(const short8*)(qp + qbase);
    short8 qf1 = *(const short8*)(qp + qbase + 32);
    __syncthreads();

    floatx4 sacc[MB];
#pragma unroll
    for (int mb = 0; mb < MB; mb++) sacc[mb] = (floatx4){0.f, 0.f, 0.f, 0.f};
#pragma unroll
    for (int mb = 0; mb < MB; mb++) {
        int srow = mb * 16 + lm;
        short8 a0 = *(const short8*)(&Ks[srow * 64 + ((lq ^ (lm & 7)) * 8)]);
        short8 a1 = *(const short8*)(&Ks[srow * 64 + (((4 + lq) ^ (lm & 7)) * 8)]);
        sacc[mb] = __builtin_amdgcn_mfma_f32_16x16x32_bf16(a0, qf0, sacc[mb], 0, 0, 0);
        sacc[mb] = __builtin_amdgcn_mfma_f32_16x16x32_bf16(a1, qf1, sacc[mb], 0, 0, 0);
    }

    float mx = -1e30f;
#pragma unroll
    for (int mb = 0; mb < MB; mb++)
#pragma unroll
        for (int r = 0; r < 4; r++) {
            int s = mb * 16 + lq * 4 + r;
            if (s < SVALID) mx = fmaxf(mx, sacc[mb][r]);
        }
    mx = fmaxf(mx, __shfl_xor(mx, 16, 64));
    mx = fmaxf(mx, __shfl_xor(mx, 32, 64));
    mx *= 0.125f;
    float sum = 0.f;
#pragma unroll
    for (int mb = 0; mb < MB; mb++)
#pragma unroll
        for (int r = 0; r < 4; r++) {
            int s = mb * 16 + lq * 4 + r;
            float e = (s < SVALID) ? __expf(sacc[mb][r] * 0.125f - mx) : 0.f;
            sacc[mb][r] = e;
            sum += e;
        }
    sum += __shfl_xor(sum, 16, 64);
    sum += __shfl_xor(sum, 32, 64);
    float inv = 1.f / sum;

    __syncthreads();

    unsigned short* Pme = Pw + w * 16 * SPAD;
#pragma unroll
    for (int mb = 0; mb < MB; mb++) {
        short4v pk;
        pk[0] = (short)f2bfbits(sacc[mb][0] * inv);
        pk[1] = (short)f2bfbits(sacc[mb][1] * inv);
        pk[2] = (short)f2bfbits(sacc[mb][2] * inv);
        pk[3] = (short)f2bfbits(sacc[mb][3] * inv);
        int chunk = (mb * 2 + (lq >> 1)) ^ (lm & 7);
        *(short4v*)(&Pme[lm * SPAD + chunk * 8 + (lq & 1) * 4]) = pk;
    }

    floatx4 oacc[4];
#pragma unroll
    for (int mb2 = 0; mb2 < 4; mb2++) oacc[mb2] = (floatx4){0.f, 0.f, 0.f, 0.f};
    for (int ks = 0; ks < KS; ks++) {
        int sch = ((ks * 4 + lq) ^ (lm & 7)) * 8;
        short8 bfrag = *(const short8*)(&Pme[lm * SPAD + sch]);
#pragma unroll
        for (int mb2 = 0; mb2 < 4; mb2++) {
            int d = mb2 * 16 + lm;
            short8 afrag = *(const short8*)(&Vt[d * SPAD + sch]);
            oacc[mb2] = __builtin_amdgcn_mfma_f32_16x16x32_bf16(afrag, bfrag, oacc[mb2], 0, 0, 0);
        }
    }

#pragma unroll
    for (int mb2 = 0; mb2 < 4; mb2++) {
        short4v ok;
        ok[0] = (short)f2bfbits(oacc[mb2][0]);
        ok[1] = (short)f2bfbits(oacc[mb2][1]);
        ok[2] = (short)f2bfbits(oacc[mb2][2]);
        ok[3] = (short)f2bfbits(oacc[mb2][3]);
        int chunk = (mb2 * 2 + (lq >> 1)) ^ (lm & 7);
        *(short4v*)(&Pme[lm * 64 + chunk * 8 + (lq & 1) * 4]) = ok;
    }
    unsigned short* op = (unsigned short*)o;
#pragma unroll
    for (int p = 0; p < 2; p++) {
        int row = p * 8 + (lane >> 3);
        int chunk = lane & 7;
        short8 ov = *(const short8*)(&Pme[row * 64 + ((chunk ^ (row & 7)) * 8)]);
        *(short8*)(op + ((size_t)(b * N + n0 + w * 16 + row)) * 512 + h * 64 + chunk * 8) = ov;
    }
}

// ---------------------------------------------------------------------------
extern "C" void kernel_launch(void* const* d_in, const int* in_sizes, int n_in,
                              void* d_out, int out_size, void* d_ws, size_t ws_size,
                              hipStream_t stream)
{
    const void* x   = d_in[0];
    const void* ctx = d_in[1];
    const void* geo = d_in[2];
    const void* g1 = d_in[3];  const void* b1 = d_in[4];
    const void* g2 = d_in[5];  const void* b2 = d_in[6];
    const void* g3 = d_in[7];  const void* b3 = d_in[8];
    const void* g4 = d_in[9];  const void* b4 = d_in[10];
    const void* cWq = d_in[11]; const void* cWk = d_in[12];
    const void* cWv = d_in[13]; const void* cWo = d_in[14];
    const void* cbo = d_in[15];
    const void* gWq = d_in[16]; const void* gWk = d_in[17];
    const void* gWv = d_in[18]; const void* gWo = d_in[19];
    const void* gbo = d_in[20];
    const void* W1 = d_in[21];  const void* bf1 = d_in[22];
    const void* W2 = d_in[23];  const void* bf2 = d_in[24];

    const int B = 4, C = 512, NN = 4096;
    const int M = B * NN;  // 16384 token rows

    char* ws = (char*)d_ws;
    size_t off = 0;
    auto alloc = [&](size_t bytes) -> void* {
        void* p = ws + off; off += (bytes + 255) & ~(size_t)255; return p;
    };
    int*   flag = (int*)alloc(256);
    float* t  = (float*)alloc((size_t)M * C * 4);        // fp32 residual stream
    bf16* u   = (bf16*)alloc((size_t)M * C * 2);         // LN out; ob aliases u
    bf16* qb  = (bf16*)alloc((size_t)M * C * 2);         // Q
    bf16* kb  = (bf16*)alloc((size_t)B * 256 * C * 2);
    bf16* vb  = (bf16*)alloc((size_t)B * 256 * C * 2);
    bf16* ctxb = (bf16*)alloc((size_t)B * 77 * 768 * 2);
    bf16* geob = (bf16*)alloc((size_t)B * 256 * 512 * 2);
    bf16* cWqT = (bf16*)alloc((size_t)512 * 512 * 2);
    bf16* cWkT = (bf16*)alloc((size_t)512 * 768 * 2);
    bf16* cWvT = (bf16*)alloc((size_t)512 * 768 * 2);
    bf16* cWoT = (bf16*)alloc((size_t)512 * 512 * 2);
    bf16* gWqT = (bf16*)alloc((size_t)512 * 512 * 2);
    bf16* gWkT = (bf16*)alloc((size_t)512 * 512 * 2);
    bf16* gWvT = (bf16*)alloc((size_t)512 * 512 * 2);
    bf16* gWoT = (bf16*)alloc((size_t)512 * 512 * 2);
    bf16* W1T  = (bf16*)alloc((size_t)2048 * 512 * 2);
    bf16* W2T  = (bf16*)alloc((size_t)512 * 2048 * 2);
    bf16* prm  = (bf16*)alloc((size_t)7680 * 2);
    bf16* ob = u;   // attention output aliases u (u dead after Q projection)

    // FFN hidden buffer: pick largest chunking the workspace allows
    int chunk;
    bf16* hb;
    size_t rem = (ws_size > off) ? (ws_size - off) : 0;
    if (rem >= (size_t)16384 * 2048 * 2) { chunk = 16384; hb = (bf16*)alloc((size_t)16384 * 2048 * 2); }
    else if (rem >= (size_t)8192 * 2048 * 2) { chunk = 8192; hb = (bf16*)alloc((size_t)8192 * 2048 * 2); }
    else { chunk = 4096; hb = qb; }  // alias qb (dead after attention)
    (void)in_sizes; (void)n_in; (void)out_size;

    // param block layout (bf16)
    bf16 *pg1 = prm, *pb1 = prm + 512, *pg2 = prm + 1024, *pb2 = prm + 1536;
    bf16 *pg3 = prm + 2048, *pb3 = prm + 2560, *pg4 = prm + 3072, *pb4 = prm + 3584;
    bf16 *pcbo = prm + 4096, *pgbo = prm + 4608, *pbf1 = prm + 5120, *pbf2 = prm + 7168;

    dim3 tb(32, 8);

    // dtype detection + input canonicalization
    detect_kernel<<<1, 256, 0, stream>>>(x, flag);
    SegTab tab;
    const void* srcs[12] = {g1, b1, g2, b2, g3, b3, g4, b4, cbo, gbo, bf1, bf2};
    int offs[12] = {0, 512, 1024, 1536, 2048, 2560, 3072, 3584, 4096, 4608, 5120, 7168};
    int cnts[12] = {512, 512, 512, 512, 512, 512, 512, 512, 512, 512, 2048, 512};
    for (int i = 0; i < 12; i++) { tab.src[i] = srcs[i]; tab.off[i] = offs[i]; tab.cnt[i] = cnts[i]; }
    param_convert_kernel<<<12, 256, 0, stream>>>(tab, prm, flag);
    convert_kernel<<<(B * 77 * 768 + 255) / 256, 256, 0, stream>>>(ctx, ctxb, flag, B * 77 * 768);
    convert_kernel<<<(B * 256 * 512 + 255) / 256, 256, 0, stream>>>(geo, geob, flag, B * 256 * 512);

    // t = transpose(x); t = t + LN1(t)
    transpose_in_kernel<<<dim3(NN / 32, C / 32, B), tb, 0, stream>>>(x, t, flag, C, NN);
    ln_kernel<0><<<M / 4, 256, 0, stream>>>(t, pg1, pb1, nullptr, M);

    // weight transposes (W is KxN row-major -> WT NxK bf16)
    transpose_w_kernel<<<dim3(512 / 32, 512 / 32), tb, 0, stream>>>(cWq, cWqT, flag, 512, 512);
    transpose_w_kernel<<<dim3(512 / 32, 768 / 32), tb, 0, stream>>>(cWk, cWkT, flag, 768, 512);
    transpose_w_kernel<<<dim3(512 / 32, 768 / 32), tb, 0, stream>>>(cWv, cWvT, flag, 768, 512);
    transpose_w_kernel<<<dim3(512 / 32, 512 / 32), tb, 0, stream>>>(cWo, cWoT, flag, 512, 512);
    transpose_w_kernel<<<dim3(512 / 32, 512 / 32), tb, 0, stream>>>(gWq, gWqT, flag, 512, 512);
    transpose_w_kernel<<<dim3(512 / 32, 512 / 32), tb, 0, stream>>>(gWk, gWkT, flag, 512, 512);
    transpose_w_kernel<<<dim3(512 / 32, 512 / 32), tb, 0, stream>>>(gWv, gWvT, flag, 512, 512);
    transpose_w_kernel<<<dim3(512 / 32, 512 / 32), tb, 0, stream>>>(gWo, gWoT, flag, 512, 512);
    transpose_w_kernel<<<dim3(2048 / 32, 512 / 32), tb, 0, stream>>>(W1, W1T, flag, 512, 2048);
    transpose_w_kernel<<<dim3(512 / 32, 2048 / 32), tb, 0, stream>>>(W2, W2T, flag, 2048, 512);

    // ---- context cross-attention ----
    ln_kernel<1><<<M / 4, 256, 0, stream>>>(t, pg2, pb2, u, M);
    gemm128<0><<<dim3(4, M / 128), 256, 0, stream>>>(u, cWqT, nullptr, qb, 512, 512);
    gemm64<0><<<dim3(8, (308 + 63) / 64), 256, 0, stream>>>(ctxb, cWkT, nullptr, kb, 308, 768, 512);
    gemm64<0><<<dim3(8, (308 + 63) / 64), 256, 0, stream>>>(ctxb, cWvT, nullptr, vb, 308, 768, 512);
    attn_mfma_kernel<128, 77><<<dim3(B * 8, NN / 64), 256, 0, stream>>>(qb, kb, vb, ob, NN);
    gemm128<2><<<dim3(4, M / 128), 256, 0, stream>>>(ob, cWoT, pcbo, t, 512, 512);

    // ---- geometry cross-attention ----
    ln_kernel<1><<<M / 4, 256, 0, stream>>>(t, pg3, pb3, u, M);
    gemm128<0><<<dim3(4, M / 128), 256, 0, stream>>>(u, gWqT, nullptr, qb, 512, 512);
    gemm64<0><<<dim3(8, 1024 / 64), 256, 0, stream>>>(geob, gWkT, nullptr, kb, 1024, 512, 512);
    gemm64<0><<<dim3(8, 1024 / 64), 256, 0, stream>>>(geob, gWvT, nullptr, vb, 1024, 512, 512);
    attn_mfma_kernel<256, 256><<<dim3(B * 8, NN / 64), 256, 0, stream>>>(qb, kb, vb, ob, NN);
    gemm128<2><<<dim3(4, M / 128), 256, 0, stream>>>(ob, gWoT, pgbo, t, 512, 512);

    // ---- FFN (ws-adaptive chunking) ----
    ln_kernel<1><<<M / 4, 256, 0, stream>>>(t, pg4, pb4, u, M);
    for (int mc = 0; mc < M / chunk; mc++) {
        bf16* uc = u + (size_t)mc * chunk * 512;
        float* tc = t + (size_t)mc * chunk * 512;
        gemm128<1><<<dim3(2048 / 128, chunk / 128), 256, 0, stream>>>(uc, W1T, pbf1, hb, 512, 2048);
        gemm128<2><<<dim3(512 / 128, chunk / 128), 256, 0, stream>>>(hb, W2T, pbf2, tc, 2048, 512);
    }

    // out = transpose(t) in detected dtype
    transpose_out_kernel<<<dim3(NN / 32, C / 32, B), tb, 0, stream>>>(t, d_out, flag, C, NN);
}

// Round 6
// 551.399 us; speedup vs baseline: 4.4136x; 1.0791x over previous
//
#include <hip/hip_runtime.h>
#include <hip/hip_bf16.h>

using bf16 = __hip_bfloat16;
typedef __attribute__((ext_vector_type(8))) short short8;
typedef __attribute__((ext_vector_type(4))) short short4v;
typedef __attribute__((ext_vector_type(4))) float floatx4;

#define DEVFN __device__ __forceinline__

DEVFN float bf2f(bf16 v) { return __bfloat162float(v); }
DEVFN bf16 f2bf(float v) { return __float2bfloat16(v); }
DEVFN float us2f(unsigned short u) {
    union { unsigned int i; float f; } c; c.i = ((unsigned int)u) << 16; return c.f;
}
DEVFN unsigned short f2bfbits(float v) {
    union { bf16 h; unsigned short u; } c; c.h = f2bf(v); return c.u;
}
// dtype-dispatched load: isf=1 -> fp32 buffer, isf=0 -> bf16 buffer
DEVFN float loadF(const void* p, size_t i, int isf) {
    return isf ? ((const float*)p)[i] : us2f(((const unsigned short*)p)[i]);
}
// async global->LDS, 16B per lane; lds dest = wave-uniform base + lane*16
DEVFN void gl_lds16(const bf16* g, short* l) {
    __builtin_amdgcn_global_load_lds(
        (const __attribute__((address_space(1))) unsigned int*)g,
        (__attribute__((address_space(3))) unsigned int*)l, 16, 0, 0);
}
// tanh-form GELU, overflow-safe (exp->inf gives th=1, exp->0 gives th=-1)
DEVFN float fast_gelu(float v) {
    float u = v * (0.7978845608028654f + 0.0356774081f * v * v);
    float e = __expf(2.f * u);
    float th = 1.f - 2.f / (e + 1.f);
    return 0.5f * v * (1.f + th);
}

// ---------------------------------------------------------------------------
// Detect input dtype: fp32 N(0,1) -> low halves random -> exp==0xFF hits.
__global__ __launch_bounds__(256) void detect_kernel(const void* x, int* flag)
{
    __shared__ int any;
    if (threadIdx.x == 0) any = 0;
    __syncthreads();
    const unsigned short* p = (const unsigned short*)x;
    int hit = 0;
    for (int i = threadIdx.x; i < 8192; i += 256) {
        if ((p[i] & 0x7F80u) == 0x7F80u) hit = 1;
    }
    if (hit) any = 1;
    __syncthreads();
    if (threadIdx.x == 0) flag[0] = any;
}

__global__ __launch_bounds__(256) void convert_kernel(
    const void* __restrict__ src, bf16* __restrict__ dst, const int* __restrict__ flag, int n)
{
    int isf = *flag;
    int i = blockIdx.x * 256 + threadIdx.x;
    if (i < n) dst[i] = f2bf(loadF(src, i, isf));
}

struct SegTab {
    const void* src[12];
    int off[12];
    int cnt[12];
};
__global__ __launch_bounds__(256) void param_convert_kernel(
    SegTab tab, bf16* __restrict__ dst, const int* __restrict__ flag)
{
    int isf = *flag;
    int s = blockIdx.x;
    const void* src = tab.src[s];
    int off = tab.off[s], cnt = tab.cnt[s];
    for (int i = threadIdx.x; i < cnt; i += 256)
        dst[off + i] = f2bf(loadF(src, i, isf));
}

// ---------------------------------------------------------------------------
// Transpose x (B,C,N) -> t (B,N,C) fp32
__global__ __launch_bounds__(256) void transpose_in_kernel(
    const void* __restrict__ x, float* __restrict__ t, const int* __restrict__ flag,
    int C, int NN)
{
    __shared__ float tile[32][33];
    int isf = *flag;
    int b = blockIdx.z;
    int n0 = blockIdx.x * 32, c0 = blockIdx.y * 32;
    int tx = threadIdx.x, ty = threadIdx.y;
#pragma unroll
    for (int i = 0; i < 4; i++)
        tile[ty + i * 8][tx] = loadF(x, ((size_t)b * C + c0 + ty + i * 8) * NN + n0 + tx, isf);
    __syncthreads();
#pragma unroll
    for (int i = 0; i < 4; i++)
        t[((size_t)b * NN + n0 + ty + i * 8) * C + c0 + tx] = tile[tx][ty + i * 8];
}

// Transpose t (B,N,C) fp32 -> out (B,C,N) in the detected output dtype
__global__ __launch_bounds__(256) void transpose_out_kernel(
    const float* __restrict__ t, void* __restrict__ o, const int* __restrict__ flag,
    int C, int NN)
{
    __shared__ float tile[32][33];
    int isf = *flag;
    int b = blockIdx.z;
    int n0 = blockIdx.x * 32, c0 = blockIdx.y * 32;
    int tx = threadIdx.x, ty = threadIdx.y;
#pragma unroll
    for (int i = 0; i < 4; i++)
        tile[ty + i * 8][tx] = t[((size_t)b * NN + n0 + ty + i * 8) * C + c0 + tx];
    __syncthreads();
#pragma unroll
    for (int i = 0; i < 4; i++) {
        size_t oi = ((size_t)b * C + c0 + ty + i * 8) * NN + n0 + tx;
        float val = tile[tx][ty + i * 8];
        if (isf) ((float*)o)[oi] = val;
        else ((bf16*)o)[oi] = f2bf(val);
    }
}

// Transpose W (K,Nc) -> WT (Nc,K) bf16
__global__ __launch_bounds__(256) void transpose_w_kernel(
    const void* __restrict__ Wm, bf16* __restrict__ WT, const int* __restrict__ flag,
    int K, int Nc)
{
    __shared__ float tile[32][33];
    int isf = *flag;
    int n0 = blockIdx.x * 32, k0 = blockIdx.y * 32;
    int tx = threadIdx.x, ty = threadIdx.y;
#pragma unroll
    for (int i = 0; i < 4; i++)
        tile[ty + i * 8][tx] = loadF(Wm, (size_t)(k0 + ty + i * 8) * Nc + n0 + tx, isf);
    __syncthreads();
#pragma unroll
    for (int i = 0; i < 4; i++)
        WT[(size_t)(n0 + ty + i * 8) * K + k0 + tx] = f2bf(tile[tx][ty + i * 8]);
}

// ---------------------------------------------------------------------------
// LayerNorm over C=512. MODE 0: t = t + LN(t) in place (fp32).
//                       MODE 1: out = bf16(LN(t)).
template <int MODE>
__global__ __launch_bounds__(256) void ln_kernel(
    float* __restrict__ t, const bf16* __restrict__ g, const bf16* __restrict__ bta,
    bf16* __restrict__ outp, int Mrows)
{
    int w = threadIdx.x >> 6, lane = threadIdx.x & 63;
    int row = blockIdx.x * 4 + w;
    if (row >= Mrows) return;
    float* xr = t + (size_t)row * 512;
    float4 v0 = *(const float4*)(xr + lane * 8);
    float4 v1 = *(const float4*)(xr + lane * 8 + 4);
    float vals[8] = {v0.x, v0.y, v0.z, v0.w, v1.x, v1.y, v1.z, v1.w};
    float s = 0.f;
#pragma unroll
    for (int i = 0; i < 8; i++) s += vals[i];
#pragma unroll
    for (int off = 32; off; off >>= 1) s += __shfl_xor(s, off, 64);
    float mu = s * (1.f / 512.f);
    float sq = 0.f;
#pragma unroll
    for (int i = 0; i < 8; i++) { float d = vals[i] - mu; sq += d * d; }
#pragma unroll
    for (int off = 32; off; off >>= 1) sq += __shfl_xor(sq, off, 64);
    float rs = rsqrtf(sq * (1.f / 512.f) + 1e-5f);
#pragma unroll
    for (int i = 0; i < 8; i++) {
        int c = lane * 8 + i;
        float y = (vals[i] - mu) * rs * bf2f(g[c]) + bf2f(bta[c]);
        if (MODE == 0) xr[c] = vals[i] + y;
        else outp[(size_t)row * 512 + c] = f2bf(y);
    }
}

// ---------------------------------------------------------------------------
// 64-tile GEMM (kept for small/ragged M): out = epi(A @ WT^T + bias)
template <int MODE>
__global__ __launch_bounds__(256) void gemm64(
    const bf16* __restrict__ A, const bf16* __restrict__ WT,
    const bf16* __restrict__ bias, void* __restrict__ outp,
    int M, int K, int Nc)
{
    __shared__ short As[64 * 32];
    __shared__ short Bs[64 * 32];
    const int tid = threadIdx.x;
    const int m0 = blockIdx.y * 64;
    const int n0 = blockIdx.x * 64;
    const int w = tid >> 6;
    const int lane = tid & 63;
    const int lm = lane & 15;
    const int lq = lane >> 4;

    floatx4 acc[4];
#pragma unroll
    for (int nb = 0; nb < 4; nb++) acc[nb] = (floatx4){0.f, 0.f, 0.f, 0.f};

    const int srow = tid >> 2;
    const int scol = (tid & 3) << 3;
    const int agrow = m0 + srow;
    const bool aok = agrow < M;
    const bf16* Aptr = A + (size_t)agrow * K + scol;
    const bf16* Bptr = WT + (size_t)(n0 + srow) * K + scol;

    for (int k0 = 0; k0 < K; k0 += 32) {
        __syncthreads();
        int4 av = make_int4(0, 0, 0, 0);
        if (aok) av = *(const int4*)(Aptr + k0);
        *(int4*)(&As[srow * 32 + scol]) = av;
        *(int4*)(&Bs[srow * 32 + scol]) = *(const int4*)(Bptr + k0);
        __syncthreads();
        short8 a = *(const short8*)(&As[(w * 16 + lm) * 32 + lq * 8]);
#pragma unroll
        for (int nb = 0; nb < 4; nb++) {
            short8 b = *(const short8*)(&Bs[(nb * 16 + lm) * 32 + lq * 8]);
            acc[nb] = __builtin_amdgcn_mfma_f32_16x16x32_bf16(a, b, acc[nb], 0, 0, 0);
        }
    }

#pragma unroll
    for (int nb = 0; nb < 4; nb++) {
        int col = n0 + nb * 16 + lm;
        float bv = bias ? bf2f(bias[col]) : 0.f;
#pragma unroll
        for (int r = 0; r < 4; r++) {
            int row = m0 + w * 16 + lq * 4 + r;
            if (row < M) {
                float v = acc[nb][r] + bv;
                if (MODE == 1) v = fast_gelu(v);
                if (MODE == 2) {
                    ((float*)outp)[(size_t)row * Nc + col] += v;
                } else {
                    ((bf16*)outp)[(size_t)row * Nc + col] = f2bf(v);
                }
            }
        }
    }
}

// ---------------------------------------------------------------------------
// 128-tile GEMM, m97 staging + TRANSPOSED accumulation: weights on the MFMA
// A-side, activations on the B-side, so each lane's 4 acc regs are 4
// consecutive OUTPUT COLUMNS of one row -> vectorizable epilogue.
// MODE 0: store bf16 (LDS-staged 16B stores); MODE 1: fast_gelu then same;
// MODE 2: float4 read-modify-write += into fp32.
// REQUIRES M%128==0, Nc%128==0, K%32==0.
template <int MODE>
__global__ __launch_bounds__(256) void gemm128(
    const bf16* __restrict__ A, const bf16* __restrict__ WT,
    const bf16* __restrict__ bias, void* __restrict__ outp,
    int K, int Nc)
{
    __shared__ short As[128 * 32];
    __shared__ short Bs[128 * 32];
    const int tid = threadIdx.x;
    const int m0 = blockIdx.y * 128;
    const int n0 = blockIdx.x * 128;
    const int w = tid >> 6, lane = tid & 63;
    const int lm = lane & 15, lq = lane >> 4;
    const int wy = w >> 1, wx = w & 1;  // wy: activation-row half, wx: col half

    // acc[cb][rb]: cb = col-block (MFMA m), rb = row-block (MFMA n)
    floatx4 acc[4][4];
#pragma unroll
    for (int cb = 0; cb < 4; cb++)
#pragma unroll
        for (int rb = 0; rb < 4; rb++) acc[cb][rb] = (floatx4){0.f, 0.f, 0.f, 0.f};

    // staging: 8 chunks of 1KB each for A and B; wave w handles chunks w*2, w*2+1.
    const int c0 = w * 2, c1 = w * 2 + 1;
    const int lr = lane >> 2;
    const int lk = (lane & 3) << 3;
    const bf16* gA0 = A + (size_t)(m0 + c0 * 16 + lr) * K + lk;
    const bf16* gA1 = A + (size_t)(m0 + c1 * 16 + lr) * K + lk;
    const bf16* gB0 = WT + (size_t)(n0 + c0 * 16 + lr) * K + lk;
    const bf16* gB1 = WT + (size_t)(n0 + c1 * 16 + lr) * K + lk;
    short* lA0 = &As[c0 * 512];
    short* lA1 = &As[c1 * 512];
    short* lB0 = &Bs[c0 * 512];
    short* lB1 = &Bs[c1 * 512];

    for (int k0 = 0; k0 < K; k0 += 32) {
        gl_lds16(gA0 + k0, lA0);
        gl_lds16(gA1 + k0, lA1);
        gl_lds16(gB0 + k0, lB0);
        gl_lds16(gB1 + k0, lB1);
        __syncthreads();
        short8 wf[4], xf[4];
#pragma unroll
        for (int cb = 0; cb < 4; cb++)   // weight rows = output cols
            wf[cb] = *(const short8*)(&Bs[(wx * 64 + cb * 16 + lm) * 32 + lq * 8]);
#pragma unroll
        for (int rb = 0; rb < 4; rb++)   // activation rows = output rows
            xf[rb] = *(const short8*)(&As[(wy * 64 + rb * 16 + lm) * 32 + lq * 8]);
#pragma unroll
        for (int cb = 0; cb < 4; cb++)
#pragma unroll
            for (int rb = 0; rb < 4; rb++)
                acc[cb][rb] = __builtin_amdgcn_mfma_f32_16x16x32_bf16(wf[cb], xf[rb], acc[cb][rb], 0, 0, 0);
        __syncthreads();
    }

    // D layout: out col n = n0+wx*64+cb*16+lq*4+r, out row m = m0+wy*64+rb*16+lm
    float4 bias4[4];
#pragma unroll
    for (int cb = 0; cb < 4; cb++) {
        if (bias) {
            const bf16* bp = bias + n0 + wx * 64 + cb * 16 + lq * 4;
            bias4[cb] = make_float4(bf2f(bp[0]), bf2f(bp[1]), bf2f(bp[2]), bf2f(bp[3]));
        } else {
            bias4[cb] = make_float4(0.f, 0.f, 0.f, 0.f);
        }
    }

    if (MODE == 2) {
        float* po = (float*)outp;
#pragma unroll
        for (int rb = 0; rb < 4; rb++) {
            size_t m = m0 + wy * 64 + rb * 16 + lm;
#pragma unroll
            for (int cb = 0; cb < 4; cb++) {
                float* p = po + m * Nc + n0 + wx * 64 + cb * 16 + lq * 4;
                float4 f = *(float4*)p;
                f.x += acc[cb][rb][0] + bias4[cb].x;
                f.y += acc[cb][rb][1] + bias4[cb].y;
                f.z += acc[cb][rb][2] + bias4[cb].z;
                f.w += acc[cb][rb][3] + bias4[cb].w;
                *(float4*)p = f;
            }
        }
    } else {
        // per-wave LDS staging (reuse As after final K-loop barrier): 16 rows x 64 cols
        unsigned short* stg = (unsigned short*)&As[w * 1024];
        unsigned short* op = (unsigned short*)outp;
#pragma unroll
        for (int rb = 0; rb < 4; rb++) {
#pragma unroll
            for (int cb = 0; cb < 4; cb++) {
                short4v pk;
#pragma unroll
                for (int r = 0; r < 4; r++) {
                    float vv = acc[cb][rb][r] + ((const float*)&bias4[cb])[r];
                    if (MODE == 1) vv = fast_gelu(vv);
                    pk[r] = (short)f2bfbits(vv);
                }
                int chunk = (cb * 2 + (lq >> 1)) ^ (lm & 7);
                *(short4v*)(&stg[lm * 64 + chunk * 8 + (lq & 1) * 4]) = pk;
            }
#pragma unroll
            for (int p = 0; p < 2; p++) {
                int row = p * 8 + (lane >> 3);
                int chunk = lane & 7;
                short8 ov = *(const short8*)(&stg[row * 64 + ((chunk ^ (row & 7)) * 8)]);
                size_t m = m0 + wy * 64 + rb * 16 + row;
                *(short8*)(op + m * Nc + n0 + wx * 64 + chunk * 8) = ov;
            }
        }
    }
}

// ---------------------------------------------------------------------------
// MFMA attention. Block = one (b,h) x 64-query tile; 4 waves, 16 q each.
template <int SPAD, int SVALID>
__global__ __launch_bounds__(256) void attn_mfma_kernel(
    const bf16* __restrict__ q, const bf16* __restrict__ k, const bf16* __restrict__ v,
    bf16* __restrict__ o, int N)
{
    constexpr int MB = SPAD / 16;   // score m-blocks over s
    constexpr int KS = SPAD / 32;   // PV k-steps over s
    __shared__ unsigned short lds[SPAD * 64 + 64 * SPAD];
    unsigned short* Ks = lds;                 // [s][64], chunk-swizzled by s&7
    unsigned short* Vt = lds + SPAD * 64;     // [d][SPAD], chunk-swizzled by d&7
    unsigned short* Pw = lds;                 // alias (after barrier): per-wave [16][SPAD]

    const int tid = threadIdx.x;
    const int b = blockIdx.x >> 3;
    const int h = blockIdx.x & 7;
    const int n0 = blockIdx.y * 64;
    const int w = tid >> 6, lane = tid & 63;
    const int lm = lane & 15, lq = lane >> 4;

    const unsigned short* kp = (const unsigned short*)k;
    const unsigned short* vp = (const unsigned short*)v;
    for (int idx = tid * 8; idx < SPAD * 64; idx += 2048) {
        int s = idx >> 6, d0 = idx & 63;
        short8 kv = {0, 0, 0, 0, 0, 0, 0, 0};
        short8 vv = {0, 0, 0, 0, 0, 0, 0, 0};
        if (s < SVALID) {
            size_t gb = ((size_t)(b * SVALID + s)) * 512 + h * 64 + d0;
            kv = *(const short8*)(kp + gb);
            vv = *(const short8*)(vp + gb);
        }
        int kc = (d0 >> 3) ^ (s & 7);
        *(short8*)(&Ks[s * 64 + kc * 8]) = kv;
        const unsigned short* vvp = (const unsigned short*)&vv;
#pragma unroll
        for (int i = 0; i < 8; i++) {
            int d = d0 + i;
            int sc = (s >> 3) ^ (d & 7);
            Vt[d * SPAD + sc * 8 + (s & 7)] = vvp[i];
        }
    }

    const int q0 = n0 + w * 16;
    const unsigned short* qp = (const unsigned short*)q;
    size_t qbase = ((size_t)(b * N + q0 + lm)) * 512 + h * 64 + lq * 8;
    short8 qf0 = *(const short8*)(qp + qbase);
    short8 qf1 = *(const short8*)(qp + qbase + 32);
    __syncthreads();

    floatx4 sacc[MB];
#pragma unroll
    for (int mb = 0; mb < MB; mb++) sacc[mb] = (floatx4){0.f, 0.f, 0.f, 0.f};
#pragma unroll
    for (int mb = 0; mb < MB; mb++) {
        int srow = mb * 16 + lm;
        short8 a0 = *(const short8*)(&Ks[srow * 64 + ((lq ^ (lm & 7)) * 8)]);
        short8 a1 = *(const short8*)(&Ks[srow * 64 + (((4 + lq) ^ (lm & 7)) * 8)]);
        sacc[mb] = __builtin_amdgcn_mfma_f32_16x16x32_bf16(a0, qf0, sacc[mb], 0, 0, 0);
        sacc[mb] = __builtin_amdgcn_mfma_f32_16x16x32_bf16(a1, qf1, sacc[mb], 0, 0, 0);
    }

    float mx = -1e30f;
#pragma unroll
    for (int mb = 0; mb < MB; mb++)
#pragma unroll
        for (int r = 0; r < 4; r++) {
            int s = mb * 16 + lq * 4 + r;
            if (s < SVALID) mx = fmaxf(mx, sacc[mb][r]);
        }
    mx = fmaxf(mx, __shfl_xor(mx, 16, 64));
    mx = fmaxf(mx, __shfl_xor(mx, 32, 64));
    mx *= 0.125f;
    float sum = 0.f;
#pragma unroll
    for (int mb = 0; mb < MB; mb++)
#pragma unroll
        for (int r = 0; r < 4; r++) {
            int s = mb * 16 + lq * 4 + r;
            float e = (s < SVALID) ? __expf(sacc[mb][r] * 0.125f - mx) : 0.f;
            sacc[mb][r] = e;
            sum += e;
        }
    sum += __shfl_xor(sum, 16, 64);
    sum += __shfl_xor(sum, 32, 64);
    float inv = 1.f / sum;

    __syncthreads();

    unsigned short* Pme = Pw + w * 16 * SPAD;
#pragma unroll
    for (int mb = 0; mb < MB; mb++) {
        short4v pk;
        pk[0] = (short)f2bfbits(sacc[mb][0] * inv);
        pk[1] = (short)f2bfbits(sacc[mb][1] * inv);
        pk[2] = (short)f2bfbits(sacc[mb][2] * inv);
        pk[3] = (short)f2bfbits(sacc[mb][3] * inv);
        int chunk = (mb * 2 + (lq >> 1)) ^ (lm & 7);
        *(short4v*)(&Pme[lm * SPAD + chunk * 8 + (lq & 1) * 4]) = pk;
    }

    floatx4 oacc[4];
#pragma unroll
    for (int mb2 = 0; mb2 < 4; mb2++) oacc[mb2] = (floatx4){0.f, 0.f, 0.f, 0.f};
    for (int ks = 0; ks < KS; ks++) {
        int sch = ((ks * 4 + lq) ^ (lm & 7)) * 8;
        short8 bfrag = *(const short8*)(&Pme[lm * SPAD + sch]);
#pragma unroll
        for (int mb2 = 0; mb2 < 4; mb2++) {
            int d = mb2 * 16 + lm;
            short8 afrag = *(const short8*)(&Vt[d * SPAD + sch]);
            oacc[mb2] = __builtin_amdgcn_mfma_f32_16x16x32_bf16(afrag, bfrag, oacc[mb2], 0, 0, 0);
        }
    }

#pragma unroll
    for (int mb2 = 0; mb2 < 4; mb2++) {
        short4v ok;
        ok[0] = (short)f2bfbits(oacc[mb2][0]);
        ok[1] = (short)f2bfbits(oacc[mb2][1]);
        ok[2] = (short)f2bfbits(oacc[mb2][2]);
        ok[3] = (short)f2bfbits(oacc[mb2][3]);
        int chunk = (mb2 * 2 + (lq >> 1)) ^ (lm & 7);
        *(short4v*)(&Pme[lm * 64 + chunk * 8 + (lq & 1) * 4]) = ok;
    }
    unsigned short* op = (unsigned short*)o;
#pragma unroll
    for (int p = 0; p < 2; p++) {
        int row = p * 8 + (lane >> 3);
        int chunk = lane & 7;
        short8 ov = *(const short8*)(&Pme[row * 64 + ((chunk ^ (row & 7)) * 8)]);
        *(short8*)(op + ((size_t)(b * N + n0 + w * 16 + row)) * 512 + h * 64 + chunk * 8) = ov;
    }
}

// ---------------------------------------------------------------------------
extern "C" void kernel_launch(void* const* d_in, const int* in_sizes, int n_in,
                              void* d_out, int out_size, void* d_ws, size_t ws_size,
                              hipStream_t stream)
{
    const void* x   = d_in[0];
    const void* ctx = d_in[1];
    const void* geo = d_in[2];
    const void* g1 = d_in[3];  const void* b1 = d_in[4];
    const void* g2 = d_in[5];  const void* b2 = d_in[6];
    const void* g3 = d_in[7];  const void* b3 = d_in[8];
    const void* g4 = d_in[9];  const void* b4 = d_in[10];
    const void* cWq = d_in[11]; const void* cWk = d_in[12];
    const void* cWv = d_in[13]; const void* cWo = d_in[14];
    const void* cbo = d_in[15];
    const void* gWq = d_in[16]; const void* gWk = d_in[17];
    const void* gWv = d_in[18]; const void* gWo = d_in[19];
    const void* gbo = d_in[20];
    const void* W1 = d_in[21];  const void* bf1 = d_in[22];
    const void* W2 = d_in[23];  const void* bf2 = d_in[24];

    const int B = 4, C = 512, NN = 4096;
    const int M = B * NN;  // 16384 token rows

    char* ws = (char*)d_ws;
    size_t off = 0;
    auto alloc = [&](size_t bytes) -> void* {
        void* p = ws + off; off += (bytes + 255) & ~(size_t)255; return p;
    };
    int*   flag = (int*)alloc(256);
    float* t  = (float*)alloc((size_t)M * C * 4);        // fp32 residual stream
    bf16* u   = (bf16*)alloc((size_t)M * C * 2);         // LN out; ob aliases u
    bf16* qb  = (bf16*)alloc((size_t)M * C * 2);         // Q
    bf16* kb  = (bf16*)alloc((size_t)B * 256 * C * 2);
    bf16* vb  = (bf16*)alloc((size_t)B * 256 * C * 2);
    bf16* ctxb = (bf16*)alloc((size_t)B * 77 * 768 * 2);
    bf16* geob = (bf16*)alloc((size_t)B * 256 * 512 * 2);
    bf16* cWqT = (bf16*)alloc((size_t)512 * 512 * 2);
    bf16* cWkT = (bf16*)alloc((size_t)512 * 768 * 2);
    bf16* cWvT = (bf16*)alloc((size_t)512 * 768 * 2);
    bf16* cWoT = (bf16*)alloc((size_t)512 * 512 * 2);
    bf16* gWqT = (bf16*)alloc((size_t)512 * 512 * 2);
    bf16* gWkT = (bf16*)alloc((size_t)512 * 512 * 2);
    bf16* gWvT = (bf16*)alloc((size_t)512 * 512 * 2);
    bf16* gWoT = (bf16*)alloc((size_t)512 * 512 * 2);
    bf16* W1T  = (bf16*)alloc((size_t)2048 * 512 * 2);
    bf16* W2T  = (bf16*)alloc((size_t)512 * 2048 * 2);
    bf16* prm  = (bf16*)alloc((size_t)7680 * 2);
    bf16* ob = u;   // attention output aliases u (u dead after Q projection)

    // FFN hidden buffer: pick largest chunking the workspace allows
    int chunk;
    bf16* hb;
    size_t rem = (ws_size > off) ? (ws_size - off) : 0;
    if (rem >= (size_t)16384 * 2048 * 2) { chunk = 16384; hb = (bf16*)alloc((size_t)16384 * 2048 * 2); }
    else if (rem >= (size_t)8192 * 2048 * 2) { chunk = 8192; hb = (bf16*)alloc((size_t)8192 * 2048 * 2); }
    else { chunk = 4096; hb = qb; }  // alias qb (dead after attention)
    (void)in_sizes; (void)n_in; (void)out_size;

    // param block layout (bf16)
    bf16 *pg1 = prm, *pb1 = prm + 512, *pg2 = prm + 1024, *pb2 = prm + 1536;
    bf16 *pg3 = prm + 2048, *pb3 = prm + 2560, *pg4 = prm + 3072, *pb4 = prm + 3584;
    bf16 *pcbo = prm + 4096, *pgbo = prm + 4608, *pbf1 = prm + 5120, *pbf2 = prm + 7168;

    dim3 tb(32, 8);

    // dtype detection + input canonicalization
    detect_kernel<<<1, 256, 0, stream>>>(x, flag);
    SegTab tab;
    const void* srcs[12] = {g1, b1, g2, b2, g3, b3, g4, b4, cbo, gbo, bf1, bf2};
    int offs[12] = {0, 512, 1024, 1536, 2048, 2560, 3072, 3584, 4096, 4608, 5120, 7168};
    int cnts[12] = {512, 512, 512, 512, 512, 512, 512, 512, 512, 512, 2048, 512};
    for (int i = 0; i < 12; i++) { tab.src[i] = srcs[i]; tab.off[i] = offs[i]; tab.cnt[i] = cnts[i]; }
    param_convert_kernel<<<12, 256, 0, stream>>>(tab, prm, flag);
    convert_kernel<<<(B * 77 * 768 + 255) / 256, 256, 0, stream>>>(ctx, ctxb, flag, B * 77 * 768);
    convert_kernel<<<(B * 256 * 512 + 255) / 256, 256, 0, stream>>>(geo, geob, flag, B * 256 * 512);

    // t = transpose(x); t = t + LN1(t)
    transpose_in_kernel<<<dim3(NN / 32, C / 32, B), tb, 0, stream>>>(x, t, flag, C, NN);
    ln_kernel<0><<<M / 4, 256, 0, stream>>>(t, pg1, pb1, nullptr, M);

    // weight transposes (W is KxN row-major -> WT NxK bf16)
    transpose_w_kernel<<<dim3(512 / 32, 512 / 32), tb, 0, stream>>>(cWq, cWqT, flag, 512, 512);
    transpose_w_kernel<<<dim3(512 / 32, 768 / 32), tb, 0, stream>>>(cWk, cWkT, flag, 768, 512);
    transpose_w_kernel<<<dim3(512 / 32, 768 / 32), tb, 0, stream>>>(cWv, cWvT, flag, 768, 512);
    transpose_w_kernel<<<dim3(512 / 32, 512 / 32), tb, 0, stream>>>(cWo, cWoT, flag, 512, 512);
    transpose_w_kernel<<<dim3(512 / 32, 512 / 32), tb, 0, stream>>>(gWq, gWqT, flag, 512, 512);
    transpose_w_kernel<<<dim3(512 / 32, 512 / 32), tb, 0, stream>>>(gWk, gWkT, flag, 512, 512);
    transpose_w_kernel<<<dim3(512 / 32, 512 / 32), tb, 0, stream>>>(gWv, gWvT, flag, 512, 512);
    transpose_w_kernel<<<dim3(512 / 32, 512 / 32), tb, 0, stream>>>(gWo, gWoT, flag, 512, 512);
    transpose_w_kernel<<<dim3(2048 / 32, 512 / 32), tb, 0, stream>>>(W1, W1T, flag, 512, 2048);
    transpose_w_kernel<<<dim3(512 / 32, 2048 / 32), tb, 0, stream>>>(W2, W2T, flag, 2048, 512);

    // ---- context cross-attention ----
    ln_kernel<1><<<M / 4, 256, 0, stream>>>(t, pg2, pb2, u, M);
    gemm128<0><<<dim3(4, M / 128), 256, 0, stream>>>(u, cWqT, nullptr, qb, 512, 512);
    gemm64<0><<<dim3(8, (308 + 63) / 64), 256, 0, stream>>>(ctxb, cWkT, nullptr, kb, 308, 768, 512);
    gemm64<0><<<dim3(8, (308 + 63) / 64), 256, 0, stream>>>(ctxb, cWvT, nullptr, vb, 308, 768, 512);
    attn_mfma_kernel<128, 77><<<dim3(B * 8, NN / 64), 256, 0, stream>>>(qb, kb, vb, ob, NN);
    gemm128<2><<<dim3(4, M / 128), 256, 0, stream>>>(ob, cWoT, pcbo, t, 512, 512);

    // ---- geometry cross-attention ----
    ln_kernel<1><<<M / 4, 256, 0, stream>>>(t, pg3, pb3, u, M);
    gemm128<0><<<dim3(4, M / 128), 256, 0, stream>>>(u, gWqT, nullptr, qb, 512, 512);
    gemm64<0><<<dim3(8, 1024 / 64), 256, 0, stream>>>(geob, gWkT, nullptr, kb, 1024, 512, 512);
    gemm64<0><<<dim3(8, 1024 / 64), 256, 0, stream>>>(geob, gWvT, nullptr, vb, 1024, 512, 512);
    attn_mfma_kernel<256, 256><<<dim3(B * 8, NN / 64), 256, 0, stream>>>(qb, kb, vb, ob, NN);
    gemm128<2><<<dim3(4, M / 128), 256, 0, stream>>>(ob, gWoT, pgbo, t, 512, 512);

    // ---- FFN (ws-adaptive chunking) ----
    ln_kernel<1><<<M / 4, 256, 0, stream>>>(t, pg4, pb4, u, M);
    for (int mc = 0; mc < M / chunk; mc++) {
        bf16* uc = u + (size_t)mc * chunk * 512;
        float* tc = t + (size_t)mc * chunk * 512;
        gemm128<1><<<dim3(2048 / 128, chunk / 128), 256, 0, stream>>>(uc, W1T, pbf1, hb, 512, 2048);
        gemm128<2><<<dim3(512 / 128, chunk / 128), 256, 0, stream>>>(hb, W2T, pbf2, tc, 2048, 512);
    }

    // out = transpose(t) in detected dtype
    transpose_out_kernel<<<dim3(NN / 32, C / 32, B), tb, 0, stream>>>(t, d_out, flag, C, NN);
}